// Round 8
// baseline (226.780 us; speedup 1.0000x reference)
//
#include <hip/hip_runtime.h>
#include <hip/hip_bf16.h>

// Problem constants (fixed by setup_inputs)
#define BB 4
#define TT 2048
#define VV 512
#define CC 512
#define HH 4
#define DD 128
#define NB2 128          // 2*NB
#define NROWS (BB*TT)    // 8192
#define QC 64            // linear-attention chunk length
#define NCH (TT/QC)      // 32 chunks per sequence
#define SST 66           // padded LDS stride (ushorts)
#define EPS 1e-12f

typedef __attribute__((ext_vector_type(8))) short bf16x8;
typedef __attribute__((ext_vector_type(4))) float f32x4;
typedef unsigned short u16;

__device__ __forceinline__ float dot4(float4 a, float4 b) {
    return a.x*b.x + a.y*b.y + a.z*b.z + a.w*b.w;
}
__device__ __forceinline__ void gl_lds16(const void* g, void* l) {
    __builtin_amdgcn_global_load_lds(
        (const __attribute__((address_space(1))) unsigned int*)g,
        (__attribute__((address_space(3))) unsigned int*)l, 16, 0, 0);
}
__device__ __forceinline__ u16 f2bu(float x) {
    __hip_bfloat16 h = __float2bfloat16(x);
    return *reinterpret_cast<u16*>(&h);
}
__device__ __forceinline__ float bu2f(u16 u) {
    __hip_bfloat16 h = *reinterpret_cast<__hip_bfloat16*>(&u);
    return __bfloat162float(h);
}

// ---------------------------------------------------------------------------
// prep_all: one launch for (a) x->bf16 cast, (b) qw/kw transpose+cast,
// (c) v_w/o_w basis GEMMs, (d) zero norms. Branch by blockIdx range.
// ---------------------------------------------------------------------------
#define PREP_CVT   4096                  // NROWS*CC/4/256 float4-blocks for x cast
#define PREP_TR    512                   // 256 32x32 tiles x 2 inputs
#define PREP_W     2048                  // 2*512*512/256
#define PREP_Z     16                    // 16384 floats / (256*4)
__global__ __launch_bounds__(256) void prep_all(
    const float* __restrict__ x, const float* __restrict__ qw,
    const float* __restrict__ kw, const float* __restrict__ basis,
    const float* __restrict__ v_coeffs, const float* __restrict__ o_coeffs,
    const float* __restrict__ out_scale,
    u16* __restrict__ xb, u16* __restrict__ wq, u16* __restrict__ wk,
    u16* __restrict__ v_wT, u16* __restrict__ o_ws, float* __restrict__ norms)
{
    __shared__ float tile[32][33];
    const int bi = blockIdx.x, t = threadIdx.x;
    if (bi < PREP_CVT) {
        int i = bi * 256 + t;
        float4 v = ((const float4*)x)[i];
        u16 h[4] = {f2bu(v.x), f2bu(v.y), f2bu(v.z), f2bu(v.w)};
        ((uint2*)xb)[i] = *(uint2*)h;
    } else if (bi < PREP_CVT + PREP_TR) {
        int id = bi - PREP_CVT;
        const int z = id >> 8; id &= 255;
        const float* in = z ? kw : qw;
        u16* outT = z ? wk : wq;
        const int bx = (id & 15) * 32, by = (id >> 4) * 32;
        const int tx = t & 31, ty = t >> 5;
        #pragma unroll
        for (int r = 0; r < 32; r += 8)
            tile[ty + r][tx] = in[(size_t)(by + ty + r) * CC + bx + tx];
        __syncthreads();
        #pragma unroll
        for (int r = 0; r < 32; r += 8)
            outT[(size_t)(bx + ty + r) * VV + by + tx] = f2bu(tile[tx][ty + r]);
    } else if (bi < PREP_CVT + PREP_TR + PREP_W) {
        int idx = (bi - PREP_CVT - PREP_TR) * 256 + t;
        const int total = VV * CC;
        if (idx < total) {
            int c = idx >> 9, vi = idx & 511;      // v_wT[c][vi]
            const float4* bp = (const float4*)(basis + (size_t)vi * NB2);
            const float4* cp = (const float4*)(v_coeffs + (size_t)c * NB2);
            float s = 0.f;
            #pragma unroll
            for (int n = 0; n < NB2 / 4; ++n) s += dot4(bp[n], cp[n]);
            v_wT[idx] = f2bu(s);
        } else {
            int idx2 = idx - total;
            int vi = idx2 >> 9, c = idx2 & 511;    // o_ws[vi][c]
            const float4* bp = (const float4*)(basis + (size_t)vi * NB2);
            const float4* cp = (const float4*)(o_coeffs + (size_t)c * NB2);
            float s = 0.f;
            #pragma unroll
            for (int n = 0; n < NB2 / 4; ++n) s += dot4(bp[n], cp[n]);
            o_ws[idx2] = f2bu(s * out_scale[0]);
        }
    } else {
        int idx = (bi - PREP_CVT - PREP_TR - PREP_W) * 256 + t;
        ((float4*)norms)[idx] = make_float4(0.f, 0.f, 0.f, 0.f);
    }
}

// ---------------------------------------------------------------------------
// bf16 MFMA GEMM body, double-buffered LDS, 128x128 tile, BK=32.
// Optional fused row-sumsq (for l2norm fusion): atomicAdd per row.
// ---------------------------------------------------------------------------
template <bool BF16OUT, bool NORMS>
__device__ __forceinline__ void gemm_body(
    const u16* __restrict__ A, const u16* __restrict__ Bt,
    void* __restrict__ Cp, int M, int N, int K, int m0, int n0,
    u16* __restrict__ As, u16* __restrict__ Bs, float* __restrict__ normp)
{
    const int t = threadIdx.x;
    const int wave = t >> 6, lane = t & 63;
    const int qq = lane >> 4, l16 = lane & 15;
    const int wm = (wave >> 1) * 64, wn = (wave & 1) * 64;

    const int sA0 = wave * 128 + lane, sA1 = sA0 + 64;
    const int r0_ = sA0 & 127, c0_ = sA0 >> 7;
    const int r1_ = sA1 & 127, c1_ = sA1 >> 7;
    const u16* ga0 = A  + (size_t)(m0 + r0_) * K + c0_ * 8;
    const u16* ga1 = A  + (size_t)(m0 + r1_) * K + c1_ * 8;
    const u16* gb0 = Bt + (size_t)(n0 + r0_) * K + c0_ * 8;
    const u16* gb1 = Bt + (size_t)(n0 + r1_) * K + c1_ * 8;
    const int lo0 = (wave * 128) * 8, lo1 = (wave * 128 + 64) * 8;

    gl_lds16(ga0, As + lo0);
    gl_lds16(ga1, As + lo1);
    gl_lds16(gb0, Bs + lo0);
    gl_lds16(gb1, Bs + lo1);

    f32x4 acc[4][4];
    #pragma unroll
    for (int i = 0; i < 4; ++i)
        #pragma unroll
        for (int j = 0; j < 4; ++j) acc[i][j] = (f32x4){0.f, 0.f, 0.f, 0.f};

    int ib = 0;
    for (int k0 = 0; k0 < K; k0 += 32, ib ^= 1) {
        __syncthreads();
        if (k0 + 32 < K) {
            const int off = (ib ^ 1) * 4096;
            gl_lds16(ga0 + k0 + 32, As + off + lo0);
            gl_lds16(ga1 + k0 + 32, As + off + lo1);
            gl_lds16(gb0 + k0 + 32, Bs + off + lo0);
            gl_lds16(gb1 + k0 + 32, Bs + off + lo1);
        }
        const u16* Ac = As + ib * 4096;
        const u16* Bc = Bs + ib * 4096;
        bf16x8 af[4], bfr[4];
        #pragma unroll
        for (int mt = 0; mt < 4; ++mt)
            af[mt] = *(const bf16x8*)&Ac[(qq * 128 + wm + mt * 16 + l16) * 8];
        #pragma unroll
        for (int nt = 0; nt < 4; ++nt)
            bfr[nt] = *(const bf16x8*)&Bc[(qq * 128 + wn + nt * 16 + l16) * 8];
        #pragma unroll
        for (int mt = 0; mt < 4; ++mt)
            #pragma unroll
            for (int nt = 0; nt < 4; ++nt)
                acc[mt][nt] = __builtin_amdgcn_mfma_f32_16x16x32_bf16(
                    af[mt], bfr[nt], acc[mt][nt], 0, 0, 0);
    }
    // C/D layout: col = lane&15, row = (lane>>4)*4 + reg
    #pragma unroll
    for (int mt = 0; mt < 4; ++mt)
        #pragma unroll
        for (int r = 0; r < 4; ++r) {
            int grow = m0 + wm + mt * 16 + qq * 4 + r;
            #pragma unroll
            for (int nt = 0; nt < 4; ++nt) {
                int gcol = n0 + wn + nt * 16 + l16;
                if (BF16OUT)
                    ((u16*)Cp)[(size_t)grow * N + gcol] = f2bu(acc[mt][nt][r]);
                else
                    ((float*)Cp)[(size_t)grow * N + gcol] = acc[mt][nt][r];
            }
        }
    if (NORMS && normp) {
        #pragma unroll
        for (int mt = 0; mt < 4; ++mt)
            #pragma unroll
            for (int r = 0; r < 4; ++r) {
                float s = 0.f;
                #pragma unroll
                for (int nt = 0; nt < 4; ++nt) {
                    float v = acc[mt][nt][r];
                    s = fmaf(v, v, s);
                }
                s += __shfl_xor(s, 1, 64);
                s += __shfl_xor(s, 2, 64);
                s += __shfl_xor(s, 4, 64);
                s += __shfl_xor(s, 8, 64);
                if (l16 == 0)
                    atomicAdd(&normp[m0 + wm + mt * 16 + qq * 4 + r], s);
            }
    }
}

// merged q/k/v projection; sections 0/1 also accumulate row sumsq
__global__ __launch_bounds__(256) void gemm_qkv(
    const u16* __restrict__ xb, const u16* __restrict__ wcat,
    u16* __restrict__ qo, u16* __restrict__ ko, u16* __restrict__ vo,
    float* __restrict__ norms)
{
    __shared__ __align__(16) u16 As[8192];
    __shared__ __align__(16) u16 Bs[8192];
    const int sec = blockIdx.x >> 2;
    u16* outp = sec == 0 ? qo : (sec == 1 ? ko : vo);
    float* np = sec == 0 ? norms : (sec == 1 ? norms + NROWS : nullptr);
    gemm_body<true, true>(xb, wcat + (size_t)sec * VV * CC, outp,
                          NROWS, CC, VV, blockIdx.y * 128, (blockIdx.x & 3) * 128,
                          As, Bs, np);
}

__global__ __launch_bounds__(256) void gemm_out(
    const u16* __restrict__ Ab, const u16* __restrict__ Btb, float* __restrict__ C)
{
    __shared__ __align__(16) u16 As[8192];
    __shared__ __align__(16) u16 Bs[8192];
    gemm_body<false, false>(Ab, Btb, C, NROWS, VV, CC,
                            blockIdx.y * 128, blockIdx.x * 128, As, Bs, nullptr);
}

// ---------------------------------------------------------------------------
// per-chunk local states (k normalized via norms_k at staging), bf16 out:
// St_local[bh][c][d][e] = sum_j lam^j * v[j][d] * khat[j][e]
// ---------------------------------------------------------------------------
__global__ __launch_bounds__(256) void state_local(
    const u16* __restrict__ kb, const u16* __restrict__ vb,
    const float* __restrict__ norms_k, const float* __restrict__ dlog,
    u16* __restrict__ statesb)
{
    __shared__ float ksA[16][132];
    __shared__ float vsA[16][132];
    const int c  = blockIdx.x;
    const int bh = blockIdx.y;
    const int b = bh >> 2, h = bh & 3;
    const float lam = 1.f / (1.f + __expf(-dlog[h]));
    const float l2lam = log2f(lam);
    const int t = threadIdx.x;
    const int tx = t & 15, ty = t >> 4;
    const int row0 = b * TT + c * QC;
    const size_t gbase = (size_t)row0 * CC + h * DD;

    float acc[8][8] = {};

    for (int j0 = 0; j0 < QC; j0 += 16) {
        __syncthreads();
        {
            const int r = t >> 4, c8 = (t & 15) * 8;
            uint4 kraw = *(const uint4*)(kb + gbase + (size_t)(j0 + r) * CC + c8);
            uint4 vraw = *(const uint4*)(vb + gbase + (size_t)(j0 + r) * CC + c8);
            const u16* kp = (const u16*)&kraw;
            const u16* vp = (const u16*)&vraw;
            const float w = exp2f((float)(j0 + r) * l2lam);
            const float rk = 1.f / fmaxf(sqrtf(norms_k[row0 + j0 + r]), EPS);
            *(float4*)&ksA[r][c8]     = make_float4(bu2f(kp[0]) * rk, bu2f(kp[1]) * rk, bu2f(kp[2]) * rk, bu2f(kp[3]) * rk);
            *(float4*)&ksA[r][c8 + 4] = make_float4(bu2f(kp[4]) * rk, bu2f(kp[5]) * rk, bu2f(kp[6]) * rk, bu2f(kp[7]) * rk);
            *(float4*)&vsA[r][c8]     = make_float4(bu2f(vp[0]) * w, bu2f(vp[1]) * w, bu2f(vp[2]) * w, bu2f(vp[3]) * w);
            *(float4*)&vsA[r][c8 + 4] = make_float4(bu2f(vp[4]) * w, bu2f(vp[5]) * w, bu2f(vp[6]) * w, bu2f(vp[7]) * w);
        }
        __syncthreads();
        #pragma unroll
        for (int jj = 0; jj < 16; ++jj) {
            float4 va0 = *(const float4*)&vsA[jj][ty * 8];
            float4 va1 = *(const float4*)&vsA[jj][ty * 8 + 4];
            float4 ka0 = *(const float4*)&ksA[jj][tx * 8];
            float4 ka1 = *(const float4*)&ksA[jj][tx * 8 + 4];
            float vd[8] = {va0.x, va0.y, va0.z, va0.w, va1.x, va1.y, va1.z, va1.w};
            float ke[8] = {ka0.x, ka0.y, ka0.z, ka0.w, ka1.x, ka1.y, ka1.z, ka1.w};
            #pragma unroll
            for (int a = 0; a < 8; ++a)
                #pragma unroll
                for (int d = 0; d < 8; ++d)
                    acc[a][d] = fmaf(vd[a], ke[d], acc[a][d]);
        }
    }
    u16* so = statesb + ((size_t)(bh * NCH + c) << 14);
    #pragma unroll
    for (int a = 0; a < 8; ++a) {
        u16 h8[8];
        #pragma unroll
        for (int d = 0; d < 8; ++d) h8[d] = f2bu(acc[a][d]);
        *(uint4*)(so + (size_t)(ty * 8 + a) * DD + tx * 8) = *(uint4*)h8;
    }
}

// ---------------------------------------------------------------------------
// suffix combine in place, software-pipelined (prefetch distance 1).
// ---------------------------------------------------------------------------
__global__ __launch_bounds__(256) void state_combine(
    const float* __restrict__ dlog, u16* __restrict__ statesb)
{
    const int bh = blockIdx.x >> 3, part = blockIdx.x & 7;
    const int h = bh & 3;
    const float lam = 1.f / (1.f + __expf(-dlog[h]));
    const float lamQ = exp2f((float)QC * log2f(lam));
    const int t = threadIdx.x;
    float run[8] = {};
    uint4* pbase = (uint4*)(statesb + ((size_t)(bh * NCH) << 14)) + part * 256 + t;
    uint4 cur = pbase[(size_t)(NCH - 1) * 2048];
    for (int c = NCH - 1; c >= 0; --c) {
        uint4 nxt = cur;
        if (c) nxt = pbase[(size_t)(c - 1) * 2048];   // prefetch overlaps below
        u16* hb = (u16*)&cur;
        uint4 outw;
        u16* ho = (u16*)&outw;
        #pragma unroll
        for (int i = 0; i < 8; ++i) {
            float tmp = bu2f(hb[i]);
            ho[i] = f2bu(run[i]);
            run[i] = fmaf(lamQ, run[i], tmp);
        }
        pbase[(size_t)c * 2048] = outw;
        cur = nxt;
    }
}

// ---------------------------------------------------------------------------
// fused MFMA attention (bf16 in, norm scales applied here):
// P[i][j] = (qraw_i . kraw_j) * decay * rsq_k[j]   (bf16 via LDS)
// out_i   = (P@V + lam^(QC-1-i) * qraw_i @ St^T) * rsq_q[i]
// ---------------------------------------------------------------------------
__global__ __launch_bounds__(256) void attention_fused(
    const u16* __restrict__ qb, const u16* __restrict__ kb,
    const u16* __restrict__ vb, const u16* __restrict__ statesb,
    const float* __restrict__ norms, const float* __restrict__ dlog,
    u16* __restrict__ retb)
{
    __shared__ __align__(16) u16 qs[QC][DD];
    __shared__ __align__(16) u16 ks[QC][DD];
    __shared__ __align__(16) u16 vsT[DD][SST];
    __shared__ __align__(16) u16 ss[QC][SST];
    __shared__ float rql[QC], rkl[QC];

    const int c = blockIdx.x, bh = blockIdx.y;
    const int b = bh >> 2, h = bh & 3;
    const float lam = 1.f / (1.f + __expf(-dlog[h]));
    const float l2lam = log2f(lam);
    const int t = threadIdx.x;
    const int row0 = b * TT + c * QC;
    const size_t base = (size_t)row0 * CC + h * DD;

    const int wave = t >> 6, lane = t & 63;
    const int quad = lane >> 4, l16 = lane & 15;
    const int r0 = wave * 16;

    // ---- stage q,k via global_load_lds ----
    {
        const int lrow = lane >> 4;
        const int lcol = (lane & 15) * 8;
        #pragma unroll
        for (int u = 0; u < 4; ++u) {
            const int r = wave * 16 + u * 4;
            gl_lds16(qb + base + (size_t)(r + lrow) * CC + lcol, &qs[r][0]);
            gl_lds16(kb + base + (size_t)(r + lrow) * CC + lcol, &ks[r][0]);
        }
    }
    // ---- rsq scales ----
    if (t < QC)            rql[t]      = 1.f / fmaxf(sqrtf(norms[row0 + t]), EPS);
    else if (t < 2 * QC)   rkl[t - QC] = 1.f / fmaxf(sqrtf(norms[NROWS + row0 + t - QC]), EPS);
    // ---- stage v transposed -> vsT[d][j] ----
    {
        const int j2 = t & 31, d0 = (t >> 5) * 16;
        const u16* v0 = vb + base + (size_t)(2 * j2) * CC + d0;
        const u16* v1 = v0 + CC;
        uint4 a0 = *(const uint4*)v0;
        uint4 a1 = *(const uint4*)(v0 + 8);
        uint4 b0 = *(const uint4*)v1;
        uint4 b1 = *(const uint4*)(v1 + 8);
        const u16* ap0 = (const u16*)&a0; const u16* ap1 = (const u16*)&a1;
        const u16* bp0 = (const u16*)&b0; const u16* bp1 = (const u16*)&b1;
        #pragma unroll
        for (int i = 0; i < 8; ++i) {
            *(unsigned int*)&vsT[d0 + i][2 * j2] =
                (unsigned int)ap0[i] | ((unsigned int)bp0[i] << 16);
            *(unsigned int*)&vsT[d0 + 8 + i][2 * j2] =
                (unsigned int)ap1[i] | ((unsigned int)bp1[i] << 16);
        }
    }
    __syncthreads();   // the only barrier

    bf16x8 aq[4];
    #pragma unroll
    for (int kq = 0; kq < 4; ++kq)
        aq[kq] = *(const bf16x8*)&qs[r0 + l16][kq * 32 + quad * 8];

    // ---- scores ----
    f32x4 accs[4];
    #pragma unroll
    for (int nt = 0; nt < 4; ++nt) accs[nt] = (f32x4){0.f, 0.f, 0.f, 0.f};
    #pragma unroll
    for (int nt = 0; nt < 4; ++nt)
        #pragma unroll
        for (int kq = 0; kq < 4; ++kq) {
            bf16x8 bk = *(const bf16x8*)&ks[nt * 16 + l16][kq * 32 + quad * 8];
            accs[nt] = __builtin_amdgcn_mfma_f32_16x16x32_bf16(aq[kq], bk, accs[nt], 0, 0, 0);
        }

    // ---- decay + mask + k-norm -> P ----
    #pragma unroll
    for (int nt = 0; nt < 4; ++nt) {
        const int j = nt * 16 + l16;
        const float rkj = rkl[j];
        #pragma unroll
        for (int rr = 0; rr < 4; ++rr) {
            const int i = r0 + quad * 4 + rr;
            const int di = j - i;
            float p = (di > 0) ? accs[nt][rr] * exp2f((float)(di - 1) * l2lam) * rkj : 0.f;
            ss[i][j] = f2bu(p);
        }
    }

    // ---- cross: q @ St^T ----
    const u16* sb = statesb + ((size_t)(bh * NCH + c) << 14);
    f32x4 accc[8];
    #pragma unroll
    for (int nt = 0; nt < 8; ++nt) accc[nt] = (f32x4){0.f, 0.f, 0.f, 0.f};
    #pragma unroll
    for (int nt = 0; nt < 8; ++nt)
        #pragma unroll
        for (int kq = 0; kq < 4; ++kq) {
            bf16x8 bs_ = *(const bf16x8*)(sb + (size_t)(nt * 16 + l16) * DD + kq * 32 + quad * 8);
            accc[nt] = __builtin_amdgcn_mfma_f32_16x16x32_bf16(aq[kq], bs_, accc[nt], 0, 0, 0);
        }

    // ---- P @ V ----
    bf16x8 ap[2];
    #pragma unroll
    for (int kj = 0; kj < 2; ++kj)
        ap[kj] = *(const bf16x8*)&ss[r0 + l16][kj * 32 + quad * 8];
    f32x4 accd[8];
    #pragma unroll
    for (int nt = 0; nt < 8; ++nt) accd[nt] = (f32x4){0.f, 0.f, 0.f, 0.f};
    #pragma unroll
    for (int nt = 0; nt < 8; ++nt)
        #pragma unroll
        for (int kj = 0; kj < 2; ++kj) {
            bf16x8 bv = *(const bf16x8*)&vsT[nt * 16 + l16][kj * 32 + quad * 8];
            accd[nt] = __builtin_amdgcn_mfma_f32_16x16x32_bf16(ap[kj], bv, accd[nt], 0, 0, 0);
        }

    // ---- combine + q-norm + bf16 store ----
    u16* rb = retb + (size_t)row0 * CC + h * DD;
    #pragma unroll
    for (int rr = 0; rr < 4; ++rr) {
        const int ii = r0 + quad * 4 + rr;
        const float wrow = exp2f((float)(QC - 1 - ii) * l2lam);
        const float rq = rql[ii];
        #pragma unroll
        for (int nt = 0; nt < 8; ++nt) {
            float val = (accd[nt][rr] + wrow * accc[nt][rr]) * rq;
            rb[(size_t)ii * CC + nt * 16 + l16] = f2bu(val);
        }
    }
}

// ---------------------------------------------------------------------------
extern "C" void kernel_launch(void* const* d_in, const int* in_sizes, int n_in,
                              void* d_out, int out_size, void* d_ws, size_t ws_size,
                              hipStream_t stream) {
    const float* x         = (const float*)d_in[0];
    const float* basis     = (const float*)d_in[1];
    const float* qw        = (const float*)d_in[2];
    const float* kw        = (const float*)d_in[3];
    const float* v_coeffs  = (const float*)d_in[4];
    const float* o_coeffs  = (const float*)d_in[5];
    const float* dlog      = (const float*)d_in[6];
    const float* out_scale = (const float*)d_in[7];
    float* out             = (float*)d_out;

    u16* p = (u16*)d_ws;
    u16* qb      = p;                                   // 8192*512 bf16
    u16* kb      = qb + (size_t)NROWS * CC;
    u16* vb      = kb + (size_t)NROWS * CC;
    u16* statesb = vb + (size_t)NROWS * CC;             // 16*32*16384 bf16
    u16* xb      = statesb + (size_t)BB * HH * NCH * DD * DD;
    u16* retb    = xb;                                  // alias: xb dead after gemm_qkv
    u16* wcat    = xb + (size_t)NROWS * CC;             // 3 x 512x512 bf16
    u16* o_ws    = wcat + 3 * (size_t)VV * CC;
    float* norms = (float*)(o_ws + (size_t)VV * CC);    // 2 x 8192 fp32 (q, k)

    // 1. all prep in one launch (also zeroes norms)
    prep_all<<<PREP_CVT + PREP_TR + PREP_W + PREP_Z, 256, 0, stream>>>(
        x, qw, kw, basis, v_coeffs, o_coeffs, out_scale,
        xb, wcat, wcat + (size_t)VV * CC, wcat + 2 * (size_t)VV * CC, o_ws, norms);
    // 2. merged q/k/v projection (bf16 out) + fused row sumsq
    gemm_qkv<<<dim3(12, NROWS / 128), 256, 0, stream>>>(xb, wcat, qb, kb, vb, norms);
    // 3. chunked linear attention (all-MFMA; norms applied downstream)
    state_local  <<<dim3(NCH, BB * HH), 256, 0, stream>>>(kb, vb, norms + NROWS,
                                                          dlog, statesb);
    state_combine<<<BB * HH * 8, 256, 0, stream>>>(dlog, statesb);
    attention_fused<<<dim3(NCH, BB * HH), 256, 0, stream>>>(qb, kb, vb, statesb,
                                                            norms, dlog, retb);
    // 4. output projection (o_ws includes out_scale), fp32 out
    gemm_out<<<dim3(CC / 128, NROWS / 128), 256, 0, stream>>>(retb, o_ws, out);
}

// Round 9
// 197.202 us; speedup vs baseline: 1.1500x; 1.1500x over previous
//
#include <hip/hip_runtime.h>
#include <hip/hip_bf16.h>

// Problem constants (fixed by setup_inputs)
#define BB 4
#define TT 2048
#define VV 512
#define CC 512
#define HH 4
#define DD 128
#define NB2 128          // 2*NB
#define NROWS (BB*TT)    // 8192
#define QC 64            // linear-attention chunk length
#define NCH (TT/QC)      // 32 chunks per sequence
#define SST 66           // padded LDS stride (ushorts)
#define EPS 1e-12f

typedef __attribute__((ext_vector_type(8))) short bf16x8;
typedef __attribute__((ext_vector_type(4))) float f32x4;
typedef unsigned short u16;

__device__ __forceinline__ void gl_lds16(const void* g, void* l) {
    __builtin_amdgcn_global_load_lds(
        (const __attribute__((address_space(1))) unsigned int*)g,
        (__attribute__((address_space(3))) unsigned int*)l, 16, 0, 0);
}
__device__ __forceinline__ u16 f2bu(float x) {
    __hip_bfloat16 h = __float2bfloat16(x);
    return *reinterpret_cast<u16*>(&h);
}
__device__ __forceinline__ float bu2f(u16 u) {
    __hip_bfloat16 h = *reinterpret_cast<__hip_bfloat16*>(&u);
    return __bfloat162float(h);
}

// ---------------------------------------------------------------------------
// prep_all: (a) x->bf16 cast, (b) qw/kw transpose+cast, (c) basis/v_coeffs/
// o_coeffs*scale -> bf16 casts, (d) zero norms. Branch by blockIdx range.
// (Weight GEMMs moved to gemm_w — the old per-thread dot product was a
//  64-lines-per-load latency disaster, ~45 us.)
// ---------------------------------------------------------------------------
#define PREP_CVT   4096                  // NROWS*CC/4/256 float4-blocks
#define PREP_TR    512                   // 256 32x32 tiles x 2 inputs
#define PREP_CB    64                    // 512*128 floats / (256*4)
#define PREP_Z     16                    // 16384 floats / (256*4)
__global__ __launch_bounds__(256) void prep_all(
    const float* __restrict__ x, const float* __restrict__ qw,
    const float* __restrict__ kw, const float* __restrict__ basis,
    const float* __restrict__ v_coeffs, const float* __restrict__ o_coeffs,
    const float* __restrict__ out_scale,
    u16* __restrict__ xb, u16* __restrict__ wq, u16* __restrict__ wk,
    u16* __restrict__ bab, u16* __restrict__ vcb, u16* __restrict__ ocb,
    float* __restrict__ norms)
{
    __shared__ float tile[32][33];
    const int bi = blockIdx.x, t = threadIdx.x;
    if (bi < PREP_CVT) {
        int i = bi * 256 + t;
        float4 v = ((const float4*)x)[i];
        u16 h[4] = {f2bu(v.x), f2bu(v.y), f2bu(v.z), f2bu(v.w)};
        ((uint2*)xb)[i] = *(uint2*)h;
    } else if (bi < PREP_CVT + PREP_TR) {
        int id = bi - PREP_CVT;
        const int z = id >> 8; id &= 255;
        const float* in = z ? kw : qw;
        u16* outT = z ? wk : wq;
        const int bx = (id & 15) * 32, by = (id >> 4) * 32;
        const int tx = t & 31, ty = t >> 5;
        #pragma unroll
        for (int r = 0; r < 32; r += 8)
            tile[ty + r][tx] = in[(size_t)(by + ty + r) * CC + bx + tx];
        __syncthreads();
        #pragma unroll
        for (int r = 0; r < 32; r += 8)
            outT[(size_t)(bx + ty + r) * VV + by + tx] = f2bu(tile[tx][ty + r]);
    } else if (bi < PREP_CVT + PREP_TR + 3 * PREP_CB) {
        int id = bi - PREP_CVT - PREP_TR;
        const int which = id / PREP_CB;        // 0=basis 1=v_coeffs 2=o_coeffs
        int i = (id - which * PREP_CB) * 256 + t;
        const float* src = which == 0 ? basis : (which == 1 ? v_coeffs : o_coeffs);
        u16* dst = which == 0 ? bab : (which == 1 ? vcb : ocb);
        const float sc = which == 2 ? out_scale[0] : 1.f;
        float4 v = ((const float4*)src)[i];
        u16 h[4] = {f2bu(v.x * sc), f2bu(v.y * sc), f2bu(v.z * sc), f2bu(v.w * sc)};
        ((uint2*)dst)[i] = *(uint2*)h;
    } else {
        int idx = (bi - PREP_CVT - PREP_TR - 3 * PREP_CB) * 256 + t;
        ((float4*)norms)[idx] = make_float4(0.f, 0.f, 0.f, 0.f);
    }
}

// ---------------------------------------------------------------------------
// bf16 MFMA GEMM body, double-buffered LDS, 128x128 tile, BK=32.
// Optional fused row-sumsq (for l2norm fusion): atomicAdd per row.
// ---------------------------------------------------------------------------
template <bool BF16OUT, bool NORMS>
__device__ __forceinline__ void gemm_body(
    const u16* __restrict__ A, const u16* __restrict__ Bt,
    void* __restrict__ Cp, int M, int N, int K, int m0, int n0,
    u16* __restrict__ As, u16* __restrict__ Bs, float* __restrict__ normp)
{
    const int t = threadIdx.x;
    const int wave = t >> 6, lane = t & 63;
    const int qq = lane >> 4, l16 = lane & 15;
    const int wm = (wave >> 1) * 64, wn = (wave & 1) * 64;

    const int sA0 = wave * 128 + lane, sA1 = sA0 + 64;
    const int r0_ = sA0 & 127, c0_ = sA0 >> 7;
    const int r1_ = sA1 & 127, c1_ = sA1 >> 7;
    const u16* ga0 = A  + (size_t)(m0 + r0_) * K + c0_ * 8;
    const u16* ga1 = A  + (size_t)(m0 + r1_) * K + c1_ * 8;
    const u16* gb0 = Bt + (size_t)(n0 + r0_) * K + c0_ * 8;
    const u16* gb1 = Bt + (size_t)(n0 + r1_) * K + c1_ * 8;
    const int lo0 = (wave * 128) * 8, lo1 = (wave * 128 + 64) * 8;

    gl_lds16(ga0, As + lo0);
    gl_lds16(ga1, As + lo1);
    gl_lds16(gb0, Bs + lo0);
    gl_lds16(gb1, Bs + lo1);

    f32x4 acc[4][4];
    #pragma unroll
    for (int i = 0; i < 4; ++i)
        #pragma unroll
        for (int j = 0; j < 4; ++j) acc[i][j] = (f32x4){0.f, 0.f, 0.f, 0.f};

    int ib = 0;
    for (int k0 = 0; k0 < K; k0 += 32, ib ^= 1) {
        __syncthreads();
        if (k0 + 32 < K) {
            const int off = (ib ^ 1) * 4096;
            gl_lds16(ga0 + k0 + 32, As + off + lo0);
            gl_lds16(ga1 + k0 + 32, As + off + lo1);
            gl_lds16(gb0 + k0 + 32, Bs + off + lo0);
            gl_lds16(gb1 + k0 + 32, Bs + off + lo1);
        }
        const u16* Ac = As + ib * 4096;
        const u16* Bc = Bs + ib * 4096;
        bf16x8 af[4], bfr[4];
        #pragma unroll
        for (int mt = 0; mt < 4; ++mt)
            af[mt] = *(const bf16x8*)&Ac[(qq * 128 + wm + mt * 16 + l16) * 8];
        #pragma unroll
        for (int nt = 0; nt < 4; ++nt)
            bfr[nt] = *(const bf16x8*)&Bc[(qq * 128 + wn + nt * 16 + l16) * 8];
        #pragma unroll
        for (int mt = 0; mt < 4; ++mt)
            #pragma unroll
            for (int nt = 0; nt < 4; ++nt)
                acc[mt][nt] = __builtin_amdgcn_mfma_f32_16x16x32_bf16(
                    af[mt], bfr[nt], acc[mt][nt], 0, 0, 0);
    }
    // C/D layout: col = lane&15, row = (lane>>4)*4 + reg
    #pragma unroll
    for (int mt = 0; mt < 4; ++mt)
        #pragma unroll
        for (int r = 0; r < 4; ++r) {
            int grow = m0 + wm + mt * 16 + qq * 4 + r;
            #pragma unroll
            for (int nt = 0; nt < 4; ++nt) {
                int gcol = n0 + wn + nt * 16 + l16;
                if (BF16OUT)
                    ((u16*)Cp)[(size_t)grow * N + gcol] = f2bu(acc[mt][nt][r]);
                else
                    ((float*)Cp)[(size_t)grow * N + gcol] = acc[mt][nt][r];
            }
        }
    if (NORMS && normp) {
        #pragma unroll
        for (int mt = 0; mt < 4; ++mt)
            #pragma unroll
            for (int r = 0; r < 4; ++r) {
                float s = 0.f;
                #pragma unroll
                for (int nt = 0; nt < 4; ++nt) {
                    float v = acc[mt][nt][r];
                    s = fmaf(v, v, s);
                }
                s += __shfl_xor(s, 1, 64);
                s += __shfl_xor(s, 2, 64);
                s += __shfl_xor(s, 4, 64);
                s += __shfl_xor(s, 8, 64);
                if (l16 == 0)
                    atomicAdd(&normp[m0 + wm + mt * 16 + qq * 4 + r], s);
            }
    }
}

// weight GEMMs via MFMA (was the 45-us latency hotspot as per-thread dots):
// sec 0: v_wT[c][vi] = sum_k v_coeffs[c][k]*basis[vi][k]   (A=vcb, Bt=bab)
// sec 1: o_ws[vi][c] = sum_k basis[vi][k]*o_coeffs_s[c][k] (A=bab, Bt=ocb)
__global__ __launch_bounds__(256) void gemm_w(
    const u16* __restrict__ bab, const u16* __restrict__ vcb,
    const u16* __restrict__ ocb, u16* __restrict__ v_wT, u16* __restrict__ o_ws)
{
    __shared__ __align__(16) u16 As[8192];
    __shared__ __align__(16) u16 Bs[8192];
    const int sec = blockIdx.x >> 2;
    const u16* A  = sec ? bab : vcb;
    const u16* Bt = sec ? ocb : bab;
    u16* C = sec ? o_ws : v_wT;
    gemm_body<true, false>(A, Bt, C, 512, 512, NB2,
                           blockIdx.y * 128, (blockIdx.x & 3) * 128, As, Bs, nullptr);
}

// merged q/k/v projection; sections 0/1 also accumulate row sumsq
__global__ __launch_bounds__(256) void gemm_qkv(
    const u16* __restrict__ xb, const u16* __restrict__ wcat,
    u16* __restrict__ qo, u16* __restrict__ ko, u16* __restrict__ vo,
    float* __restrict__ norms)
{
    __shared__ __align__(16) u16 As[8192];
    __shared__ __align__(16) u16 Bs[8192];
    const int sec = blockIdx.x >> 2;
    u16* outp = sec == 0 ? qo : (sec == 1 ? ko : vo);
    float* np = sec == 0 ? norms : (sec == 1 ? norms + NROWS : nullptr);
    gemm_body<true, true>(xb, wcat + (size_t)sec * VV * CC, outp,
                          NROWS, CC, VV, blockIdx.y * 128, (blockIdx.x & 3) * 128,
                          As, Bs, np);
}

__global__ __launch_bounds__(256) void gemm_out(
    const u16* __restrict__ Ab, const u16* __restrict__ Btb, float* __restrict__ C)
{
    __shared__ __align__(16) u16 As[8192];
    __shared__ __align__(16) u16 Bs[8192];
    gemm_body<false, false>(Ab, Btb, C, NROWS, VV, CC,
                            blockIdx.y * 128, blockIdx.x * 128, As, Bs, nullptr);
}

// ---------------------------------------------------------------------------
// per-chunk local states (k normalized via norms_k at staging), bf16 out:
// St_local[bh][c][d][e] = sum_j lam^j * v[j][d] * khat[j][e]
// ---------------------------------------------------------------------------
__global__ __launch_bounds__(256) void state_local(
    const u16* __restrict__ kb, const u16* __restrict__ vb,
    const float* __restrict__ norms_k, const float* __restrict__ dlog,
    u16* __restrict__ statesb)
{
    __shared__ float ksA[16][132];
    __shared__ float vsA[16][132];
    const int c  = blockIdx.x;
    const int bh = blockIdx.y;
    const int b = bh >> 2, h = bh & 3;
    const float lam = 1.f / (1.f + __expf(-dlog[h]));
    const float l2lam = log2f(lam);
    const int t = threadIdx.x;
    const int tx = t & 15, ty = t >> 4;
    const int row0 = b * TT + c * QC;
    const size_t gbase = (size_t)row0 * CC + h * DD;

    float acc[8][8] = {};

    for (int j0 = 0; j0 < QC; j0 += 16) {
        __syncthreads();
        {
            const int r = t >> 4, c8 = (t & 15) * 8;
            uint4 kraw = *(const uint4*)(kb + gbase + (size_t)(j0 + r) * CC + c8);
            uint4 vraw = *(const uint4*)(vb + gbase + (size_t)(j0 + r) * CC + c8);
            const u16* kp = (const u16*)&kraw;
            const u16* vp = (const u16*)&vraw;
            const float w = exp2f((float)(j0 + r) * l2lam);
            const float rk = 1.f / fmaxf(sqrtf(norms_k[row0 + j0 + r]), EPS);
            *(float4*)&ksA[r][c8]     = make_float4(bu2f(kp[0]) * rk, bu2f(kp[1]) * rk, bu2f(kp[2]) * rk, bu2f(kp[3]) * rk);
            *(float4*)&ksA[r][c8 + 4] = make_float4(bu2f(kp[4]) * rk, bu2f(kp[5]) * rk, bu2f(kp[6]) * rk, bu2f(kp[7]) * rk);
            *(float4*)&vsA[r][c8]     = make_float4(bu2f(vp[0]) * w, bu2f(vp[1]) * w, bu2f(vp[2]) * w, bu2f(vp[3]) * w);
            *(float4*)&vsA[r][c8 + 4] = make_float4(bu2f(vp[4]) * w, bu2f(vp[5]) * w, bu2f(vp[6]) * w, bu2f(vp[7]) * w);
        }
        __syncthreads();
        #pragma unroll
        for (int jj = 0; jj < 16; ++jj) {
            float4 va0 = *(const float4*)&vsA[jj][ty * 8];
            float4 va1 = *(const float4*)&vsA[jj][ty * 8 + 4];
            float4 ka0 = *(const float4*)&ksA[jj][tx * 8];
            float4 ka1 = *(const float4*)&ksA[jj][tx * 8 + 4];
            float vd[8] = {va0.x, va0.y, va0.z, va0.w, va1.x, va1.y, va1.z, va1.w};
            float ke[8] = {ka0.x, ka0.y, ka0.z, ka0.w, ka1.x, ka1.y, ka1.z, ka1.w};
            #pragma unroll
            for (int a = 0; a < 8; ++a)
                #pragma unroll
                for (int d = 0; d < 8; ++d)
                    acc[a][d] = fmaf(vd[a], ke[d], acc[a][d]);
        }
    }
    u16* so = statesb + ((size_t)(bh * NCH + c) << 14);
    #pragma unroll
    for (int a = 0; a < 8; ++a) {
        u16 h8[8];
        #pragma unroll
        for (int d = 0; d < 8; ++d) h8[d] = f2bu(acc[a][d]);
        *(uint4*)(so + (size_t)(ty * 8 + a) * DD + tx * 8) = *(uint4*)h8;
    }
}

// ---------------------------------------------------------------------------
// suffix combine in place, software-pipelined (prefetch distance 1).
// ---------------------------------------------------------------------------
__global__ __launch_bounds__(256) void state_combine(
    const float* __restrict__ dlog, u16* __restrict__ statesb)
{
    const int bh = blockIdx.x >> 3, part = blockIdx.x & 7;
    const int h = bh & 3;
    const float lam = 1.f / (1.f + __expf(-dlog[h]));
    const float lamQ = exp2f((float)QC * log2f(lam));
    const int t = threadIdx.x;
    float run[8] = {};
    uint4* pbase = (uint4*)(statesb + ((size_t)(bh * NCH) << 14)) + part * 256 + t;
    uint4 cur = pbase[(size_t)(NCH - 1) * 2048];
    for (int c = NCH - 1; c >= 0; --c) {
        uint4 nxt = cur;
        if (c) nxt = pbase[(size_t)(c - 1) * 2048];   // prefetch overlaps below
        u16* hb = (u16*)&cur;
        uint4 outw;
        u16* ho = (u16*)&outw;
        #pragma unroll
        for (int i = 0; i < 8; ++i) {
            float tmp = bu2f(hb[i]);
            ho[i] = f2bu(run[i]);
            run[i] = fmaf(lamQ, run[i], tmp);
        }
        pbase[(size_t)c * 2048] = outw;
        cur = nxt;
    }
}

// ---------------------------------------------------------------------------
// fused MFMA attention (bf16 in, norm scales applied here):
// P[i][j] = (qraw_i . kraw_j) * decay * rsq_k[j]   (bf16 via LDS)
// out_i   = (P@V + lam^(QC-1-i) * qraw_i @ St^T) * rsq_q[i]
// ---------------------------------------------------------------------------
__global__ __launch_bounds__(256) void attention_fused(
    const u16* __restrict__ qb, const u16* __restrict__ kb,
    const u16* __restrict__ vb, const u16* __restrict__ statesb,
    const float* __restrict__ norms, const float* __restrict__ dlog,
    u16* __restrict__ retb)
{
    __shared__ __align__(16) u16 qs[QC][DD];
    __shared__ __align__(16) u16 ks[QC][DD];
    __shared__ __align__(16) u16 vsT[DD][SST];
    __shared__ __align__(16) u16 ss[QC][SST];
    __shared__ float rql[QC], rkl[QC];

    const int c = blockIdx.x, bh = blockIdx.y;
    const int b = bh >> 2, h = bh & 3;
    const float lam = 1.f / (1.f + __expf(-dlog[h]));
    const float l2lam = log2f(lam);
    const int t = threadIdx.x;
    const int row0 = b * TT + c * QC;
    const size_t base = (size_t)row0 * CC + h * DD;

    const int wave = t >> 6, lane = t & 63;
    const int quad = lane >> 4, l16 = lane & 15;
    const int r0 = wave * 16;

    // ---- stage q,k via global_load_lds ----
    {
        const int lrow = lane >> 4;
        const int lcol = (lane & 15) * 8;
        #pragma unroll
        for (int u = 0; u < 4; ++u) {
            const int r = wave * 16 + u * 4;
            gl_lds16(qb + base + (size_t)(r + lrow) * CC + lcol, &qs[r][0]);
            gl_lds16(kb + base + (size_t)(r + lrow) * CC + lcol, &ks[r][0]);
        }
    }
    // ---- rsq scales ----
    if (t < QC)            rql[t]      = 1.f / fmaxf(sqrtf(norms[row0 + t]), EPS);
    else if (t < 2 * QC)   rkl[t - QC] = 1.f / fmaxf(sqrtf(norms[NROWS + row0 + t - QC]), EPS);
    // ---- stage v transposed -> vsT[d][j] ----
    {
        const int j2 = t & 31, d0 = (t >> 5) * 16;
        const u16* v0 = vb + base + (size_t)(2 * j2) * CC + d0;
        const u16* v1 = v0 + CC;
        uint4 a0 = *(const uint4*)v0;
        uint4 a1 = *(const uint4*)(v0 + 8);
        uint4 b0 = *(const uint4*)v1;
        uint4 b1 = *(const uint4*)(v1 + 8);
        const u16* ap0 = (const u16*)&a0; const u16* ap1 = (const u16*)&a1;
        const u16* bp0 = (const u16*)&b0; const u16* bp1 = (const u16*)&b1;
        #pragma unroll
        for (int i = 0; i < 8; ++i) {
            *(unsigned int*)&vsT[d0 + i][2 * j2] =
                (unsigned int)ap0[i] | ((unsigned int)bp0[i] << 16);
            *(unsigned int*)&vsT[d0 + 8 + i][2 * j2] =
                (unsigned int)ap1[i] | ((unsigned int)bp1[i] << 16);
        }
    }
    __syncthreads();   // the only barrier

    bf16x8 aq[4];
    #pragma unroll
    for (int kq = 0; kq < 4; ++kq)
        aq[kq] = *(const bf16x8*)&qs[r0 + l16][kq * 32 + quad * 8];

    // ---- scores ----
    f32x4 accs[4];
    #pragma unroll
    for (int nt = 0; nt < 4; ++nt) accs[nt] = (f32x4){0.f, 0.f, 0.f, 0.f};
    #pragma unroll
    for (int nt = 0; nt < 4; ++nt)
        #pragma unroll
        for (int kq = 0; kq < 4; ++kq) {
            bf16x8 bk = *(const bf16x8*)&ks[nt * 16 + l16][kq * 32 + quad * 8];
            accs[nt] = __builtin_amdgcn_mfma_f32_16x16x32_bf16(aq[kq], bk, accs[nt], 0, 0, 0);
        }

    // ---- decay + mask + k-norm -> P ----
    #pragma unroll
    for (int nt = 0; nt < 4; ++nt) {
        const int j = nt * 16 + l16;
        const float rkj = rkl[j];
        #pragma unroll
        for (int rr = 0; rr < 4; ++rr) {
            const int i = r0 + quad * 4 + rr;
            const int di = j - i;
            float p = (di > 0) ? accs[nt][rr] * exp2f((float)(di - 1) * l2lam) * rkj : 0.f;
            ss[i][j] = f2bu(p);
        }
    }

    // ---- cross: q @ St^T ----
    const u16* sb = statesb + ((size_t)(bh * NCH + c) << 14);
    f32x4 accc[8];
    #pragma unroll
    for (int nt = 0; nt < 8; ++nt) accc[nt] = (f32x4){0.f, 0.f, 0.f, 0.f};
    #pragma unroll
    for (int nt = 0; nt < 8; ++nt)
        #pragma unroll
        for (int kq = 0; kq < 4; ++kq) {
            bf16x8 bs_ = *(const bf16x8*)(sb + (size_t)(nt * 16 + l16) * DD + kq * 32 + quad * 8);
            accc[nt] = __builtin_amdgcn_mfma_f32_16x16x32_bf16(aq[kq], bs_, accc[nt], 0, 0, 0);
        }

    // ---- P @ V ----
    bf16x8 ap[2];
    #pragma unroll
    for (int kj = 0; kj < 2; ++kj)
        ap[kj] = *(const bf16x8*)&ss[r0 + l16][kj * 32 + quad * 8];
    f32x4 accd[8];
    #pragma unroll
    for (int nt = 0; nt < 8; ++nt) accd[nt] = (f32x4){0.f, 0.f, 0.f, 0.f};
    #pragma unroll
    for (int nt = 0; nt < 8; ++nt)
        #pragma unroll
        for (int kj = 0; kj < 2; ++kj) {
            bf16x8 bv = *(const bf16x8*)&vsT[nt * 16 + l16][kj * 32 + quad * 8];
            accd[nt] = __builtin_amdgcn_mfma_f32_16x16x32_bf16(ap[kj], bv, accd[nt], 0, 0, 0);
        }

    // ---- combine + q-norm + bf16 store ----
    u16* rb = retb + (size_t)row0 * CC + h * DD;
    #pragma unroll
    for (int rr = 0; rr < 4; ++rr) {
        const int ii = r0 + quad * 4 + rr;
        const float wrow = exp2f((float)(QC - 1 - ii) * l2lam);
        const float rq = rql[ii];
        #pragma unroll
        for (int nt = 0; nt < 8; ++nt) {
            float val = (accd[nt][rr] + wrow * accc[nt][rr]) * rq;
            rb[(size_t)ii * CC + nt * 16 + l16] = f2bu(val);
        }
    }
}

// ---------------------------------------------------------------------------
extern "C" void kernel_launch(void* const* d_in, const int* in_sizes, int n_in,
                              void* d_out, int out_size, void* d_ws, size_t ws_size,
                              hipStream_t stream) {
    const float* x         = (const float*)d_in[0];
    const float* basis     = (const float*)d_in[1];
    const float* qw        = (const float*)d_in[2];
    const float* kw        = (const float*)d_in[3];
    const float* v_coeffs  = (const float*)d_in[4];
    const float* o_coeffs  = (const float*)d_in[5];
    const float* dlog      = (const float*)d_in[6];
    const float* out_scale = (const float*)d_in[7];
    float* out             = (float*)d_out;

    u16* p = (u16*)d_ws;
    u16* qb      = p;                                   // 8192*512 bf16
    u16* kb      = qb + (size_t)NROWS * CC;
    u16* vb      = kb + (size_t)NROWS * CC;
    u16* statesb = vb + (size_t)NROWS * CC;             // 16*32*16384 bf16
    u16* xb      = statesb + (size_t)BB * HH * NCH * DD * DD;
    u16* retb    = xb;                                  // alias: xb dead after gemm_qkv
    u16* wcat    = xb + (size_t)NROWS * CC;             // 3 x 512x512 bf16
    u16* o_ws    = wcat + 3 * (size_t)VV * CC;
    float* norms = (float*)(o_ws + (size_t)VV * CC);    // 2 x 8192 fp32 (q, k)
    u16* bab     = (u16*)(norms + 2 * NROWS);           // 512*128 bf16
    u16* vcb     = bab + (size_t)VV * NB2;
    u16* ocb     = vcb + (size_t)VV * NB2;

    // 1. casts / transposes / norm-zero in one launch
    prep_all<<<PREP_CVT + PREP_TR + 3 * PREP_CB + PREP_Z, 256, 0, stream>>>(
        x, qw, kw, basis, v_coeffs, o_coeffs, out_scale,
        xb, wcat, wcat + (size_t)VV * CC, bab, vcb, ocb, norms);
    // 2. weight GEMMs via MFMA (v_wT -> wcat sec 2, o_ws)
    gemm_w<<<dim3(8, 4), 256, 0, stream>>>(bab, vcb, ocb,
                                           wcat + 2 * (size_t)VV * CC, o_ws);
    // 3. merged q/k/v projection (bf16 out) + fused row sumsq
    gemm_qkv<<<dim3(12, NROWS / 128), 256, 0, stream>>>(xb, wcat, qb, kb, vb, norms);
    // 4. chunked linear attention (all-MFMA; norms applied downstream)
    state_local  <<<dim3(NCH, BB * HH), 256, 0, stream>>>(kb, vb, norms + NROWS,
                                                          dlog, statesb);
    state_combine<<<BB * HH * 8, 256, 0, stream>>>(dlog, statesb);
    attention_fused<<<dim3(NCH, BB * HH), 256, 0, stream>>>(qb, kb, vb, statesb,
                                                            norms, dlog, retb);
    // 5. output projection (o_ws includes out_scale), fp32 out
    gemm_out<<<dim3(CC / 128, NROWS / 128), 256, 0, stream>>>(retb, o_ws, out);
}

// Round 10
// 181.610 us; speedup vs baseline: 1.2487x; 1.0859x over previous
//
#include <hip/hip_runtime.h>
#include <hip/hip_bf16.h>

// Problem constants (fixed by setup_inputs)
#define BB 4
#define TT 2048
#define VV 512
#define CC 512
#define HH 4
#define DD 128
#define NB2 128          // 2*NB
#define NROWS (BB*TT)    // 8192
#define QC 64            // linear-attention chunk length
#define NCH (TT/QC)      // 32 chunks per sequence
#define SST 66           // padded LDS stride (ushorts)
#define EPS 1e-12f

typedef __attribute__((ext_vector_type(8))) short bf16x8;
typedef __attribute__((ext_vector_type(4))) float f32x4;
typedef unsigned short u16;

__device__ __forceinline__ void gl_lds16(const void* g, void* l) {
    __builtin_amdgcn_global_load_lds(
        (const __attribute__((address_space(1))) unsigned int*)g,
        (__attribute__((address_space(3))) unsigned int*)l, 16, 0, 0);
}
__device__ __forceinline__ u16 f2bu(float x) {
    __hip_bfloat16 h = __float2bfloat16(x);
    return *reinterpret_cast<u16*>(&h);
}
__device__ __forceinline__ float bu2f(u16 u) {
    __hip_bfloat16 h = *reinterpret_cast<__hip_bfloat16*>(&u);
    return __bfloat162float(h);
}

// ---------------------------------------------------------------------------
// prep_all: (a) x->bf16 cast, (b) qw/kw transpose+cast, (c) basis/v_coeffs/
// o_coeffs*scale -> bf16 casts, (d) zero norms. Branch by blockIdx range.
// ---------------------------------------------------------------------------
#define PREP_CVT   4096                  // NROWS*CC/4/256 float4-blocks
#define PREP_TR    512                   // 256 32x32 tiles x 2 inputs
#define PREP_CB    64                    // 512*128 floats / (256*4)
#define PREP_Z     16                    // 16384 floats / (256*4)
__global__ __launch_bounds__(256) void prep_all(
    const float* __restrict__ x, const float* __restrict__ qw,
    const float* __restrict__ kw, const float* __restrict__ basis,
    const float* __restrict__ v_coeffs, const float* __restrict__ o_coeffs,
    const float* __restrict__ out_scale,
    u16* __restrict__ xb, u16* __restrict__ wq, u16* __restrict__ wk,
    u16* __restrict__ bab, u16* __restrict__ vcb, u16* __restrict__ ocb,
    float* __restrict__ norms)
{
    __shared__ float tile[32][33];
    const int bi = blockIdx.x, t = threadIdx.x;
    if (bi < PREP_CVT) {
        int i = bi * 256 + t;
        float4 v = ((const float4*)x)[i];
        u16 h[4] = {f2bu(v.x), f2bu(v.y), f2bu(v.z), f2bu(v.w)};
        ((uint2*)xb)[i] = *(uint2*)h;
    } else if (bi < PREP_CVT + PREP_TR) {
        int id = bi - PREP_CVT;
        const int z = id >> 8; id &= 255;
        const float* in = z ? kw : qw;
        u16* outT = z ? wk : wq;
        const int bx = (id & 15) * 32, by = (id >> 4) * 32;
        const int tx = t & 31, ty = t >> 5;
        #pragma unroll
        for (int r = 0; r < 32; r += 8)
            tile[ty + r][tx] = in[(size_t)(by + ty + r) * CC + bx + tx];
        __syncthreads();
        #pragma unroll
        for (int r = 0; r < 32; r += 8)
            outT[(size_t)(bx + ty + r) * VV + by + tx] = f2bu(tile[tx][ty + r]);
    } else if (bi < PREP_CVT + PREP_TR + 3 * PREP_CB) {
        int id = bi - PREP_CVT - PREP_TR;
        const int which = id / PREP_CB;        // 0=basis 1=v_coeffs 2=o_coeffs
        int i = (id - which * PREP_CB) * 256 + t;
        const float* src = which == 0 ? basis : (which == 1 ? v_coeffs : o_coeffs);
        u16* dst = which == 0 ? bab : (which == 1 ? vcb : ocb);
        const float sc = which == 2 ? out_scale[0] : 1.f;
        float4 v = ((const float4*)src)[i];
        u16 h[4] = {f2bu(v.x * sc), f2bu(v.y * sc), f2bu(v.z * sc), f2bu(v.w * sc)};
        ((uint2*)dst)[i] = *(uint2*)h;
    } else {
        int idx = (bi - PREP_CVT - PREP_TR - 3 * PREP_CB) * 256 + t;
        ((float4*)norms)[idx] = make_float4(0.f, 0.f, 0.f, 0.f);
    }
}

// ---------------------------------------------------------------------------
// bf16 MFMA GEMM body, double-buffered LDS, 128x128 tile, BK=32.
// Staging slot map: slot = row*4 + j, stored chunk c = (j - (row>>1)) & 3.
//  -> 4 consecutive lanes cover one row's 64B K-slab (1 coalesced line req,
//     4x fewer VMEM requests than the old chunk-major map), and the rotation
//     makes the fragment ds_read_b128 2-way-per-bank (free).
// Fragment read: chunk qq of row r lives at slot r*4 + ((qq + (r>>1)) & 3).
// ---------------------------------------------------------------------------
template <bool BF16OUT, bool NORMS>
__device__ __forceinline__ void gemm_body(
    const u16* __restrict__ A, const u16* __restrict__ Bt,
    void* __restrict__ Cp, int M, int N, int K, int m0, int n0,
    u16* __restrict__ As, u16* __restrict__ Bs, float* __restrict__ normp)
{
    const int t = threadIdx.x;
    const int wave = t >> 6, lane = t & 63;
    const int qq = lane >> 4, l16 = lane & 15;
    const int wm = (wave >> 1) * 64, wn = (wave & 1) * 64;

    const int s0 = wave * 128 + lane, s1 = s0 + 64;
    const int r0_ = s0 >> 2, c0_ = ((s0 & 3) - (r0_ >> 1)) & 3;
    const int r1_ = s1 >> 2, c1_ = ((s1 & 3) - (r1_ >> 1)) & 3;
    const u16* ga0 = A  + (size_t)(m0 + r0_) * K + c0_ * 8;
    const u16* ga1 = A  + (size_t)(m0 + r1_) * K + c1_ * 8;
    const u16* gb0 = Bt + (size_t)(n0 + r0_) * K + c0_ * 8;
    const u16* gb1 = Bt + (size_t)(n0 + r1_) * K + c1_ * 8;
    const int lo0 = (wave * 128) * 8, lo1 = (wave * 128 + 64) * 8;

    gl_lds16(ga0, As + lo0);
    gl_lds16(ga1, As + lo1);
    gl_lds16(gb0, Bs + lo0);
    gl_lds16(gb1, Bs + lo1);

    f32x4 acc[4][4];
    #pragma unroll
    for (int i = 0; i < 4; ++i)
        #pragma unroll
        for (int j = 0; j < 4; ++j) acc[i][j] = (f32x4){0.f, 0.f, 0.f, 0.f};

    int ib = 0;
    for (int k0 = 0; k0 < K; k0 += 32, ib ^= 1) {
        __syncthreads();
        if (k0 + 32 < K) {
            const int off = (ib ^ 1) * 4096;
            gl_lds16(ga0 + k0 + 32, As + off + lo0);
            gl_lds16(ga1 + k0 + 32, As + off + lo1);
            gl_lds16(gb0 + k0 + 32, Bs + off + lo0);
            gl_lds16(gb1 + k0 + 32, Bs + off + lo1);
        }
        const u16* Ac = As + ib * 4096;
        const u16* Bc = Bs + ib * 4096;
        bf16x8 af[4], bfr[4];
        #pragma unroll
        for (int mt = 0; mt < 4; ++mt) {
            const int r = wm + mt * 16 + l16;
            af[mt] = *(const bf16x8*)&Ac[(r * 4 + ((qq + (r >> 1)) & 3)) * 8];
        }
        #pragma unroll
        for (int nt = 0; nt < 4; ++nt) {
            const int r = wn + nt * 16 + l16;
            bfr[nt] = *(const bf16x8*)&Bc[(r * 4 + ((qq + (r >> 1)) & 3)) * 8];
        }
        #pragma unroll
        for (int mt = 0; mt < 4; ++mt)
            #pragma unroll
            for (int nt = 0; nt < 4; ++nt)
                acc[mt][nt] = __builtin_amdgcn_mfma_f32_16x16x32_bf16(
                    af[mt], bfr[nt], acc[mt][nt], 0, 0, 0);
    }
    // C/D layout: col = lane&15, row = (lane>>4)*4 + reg
    #pragma unroll
    for (int mt = 0; mt < 4; ++mt)
        #pragma unroll
        for (int r = 0; r < 4; ++r) {
            int grow = m0 + wm + mt * 16 + qq * 4 + r;
            #pragma unroll
            for (int nt = 0; nt < 4; ++nt) {
                int gcol = n0 + wn + nt * 16 + l16;
                if (BF16OUT)
                    ((u16*)Cp)[(size_t)grow * N + gcol] = f2bu(acc[mt][nt][r]);
                else
                    ((float*)Cp)[(size_t)grow * N + gcol] = acc[mt][nt][r];
            }
        }
    if (NORMS && normp) {
        #pragma unroll
        for (int mt = 0; mt < 4; ++mt)
            #pragma unroll
            for (int r = 0; r < 4; ++r) {
                float s = 0.f;
                #pragma unroll
                for (int nt = 0; nt < 4; ++nt) {
                    float v = acc[mt][nt][r];
                    s = fmaf(v, v, s);
                }
                s += __shfl_xor(s, 1, 64);
                s += __shfl_xor(s, 2, 64);
                s += __shfl_xor(s, 4, 64);
                s += __shfl_xor(s, 8, 64);
                if (l16 == 0)
                    atomicAdd(&normp[m0 + wm + mt * 16 + qq * 4 + r], s);
            }
    }
}

// weight GEMMs via MFMA:
// sec 0: v_wT[c][vi] = sum_k v_coeffs[c][k]*basis[vi][k]   (A=vcb, Bt=bab)
// sec 1: o_ws[vi][c] = sum_k basis[vi][k]*o_coeffs_s[c][k] (A=bab, Bt=ocb)
__global__ __launch_bounds__(256) void gemm_w(
    const u16* __restrict__ bab, const u16* __restrict__ vcb,
    const u16* __restrict__ ocb, u16* __restrict__ v_wT, u16* __restrict__ o_ws)
{
    __shared__ __align__(16) u16 As[8192];
    __shared__ __align__(16) u16 Bs[8192];
    const int sec = blockIdx.x >> 2;
    const u16* A  = sec ? bab : vcb;
    const u16* Bt = sec ? ocb : bab;
    u16* C = sec ? o_ws : v_wT;
    gemm_body<true, false>(A, Bt, C, 512, 512, NB2,
                           blockIdx.y * 128, (blockIdx.x & 3) * 128, As, Bs, nullptr);
}

// merged q/k/v projection; sections 0/1 also accumulate row sumsq
__global__ __launch_bounds__(256) void gemm_qkv(
    const u16* __restrict__ xb, const u16* __restrict__ wcat,
    u16* __restrict__ qo, u16* __restrict__ ko, u16* __restrict__ vo,
    float* __restrict__ norms)
{
    __shared__ __align__(16) u16 As[8192];
    __shared__ __align__(16) u16 Bs[8192];
    const int sec = blockIdx.x >> 2;
    u16* outp = sec == 0 ? qo : (sec == 1 ? ko : vo);
    float* np = sec == 0 ? norms : (sec == 1 ? norms + NROWS : nullptr);
    gemm_body<true, true>(xb, wcat + (size_t)sec * VV * CC, outp,
                          NROWS, CC, VV, blockIdx.y * 128, (blockIdx.x & 3) * 128,
                          As, Bs, np);
}

__global__ __launch_bounds__(256) void gemm_out(
    const u16* __restrict__ Ab, const u16* __restrict__ Btb, float* __restrict__ C)
{
    __shared__ __align__(16) u16 As[8192];
    __shared__ __align__(16) u16 Bs[8192];
    gemm_body<false, false>(Ab, Btb, C, NROWS, VV, CC,
                            blockIdx.y * 128, blockIdx.x * 128, As, Bs, nullptr);
}

// ---------------------------------------------------------------------------
// per-chunk local states (k normalized via norms_k at staging), bf16 out:
// St_local[bh][c][d][e] = sum_j lam^j * v[j][d] * khat[j][e]
// ---------------------------------------------------------------------------
__global__ __launch_bounds__(256) void state_local(
    const u16* __restrict__ kb, const u16* __restrict__ vb,
    const float* __restrict__ norms_k, const float* __restrict__ dlog,
    u16* __restrict__ statesb)
{
    __shared__ float ksA[16][132];
    __shared__ float vsA[16][132];
    const int c  = blockIdx.x;
    const int bh = blockIdx.y;
    const int b = bh >> 2, h = bh & 3;
    const float lam = 1.f / (1.f + __expf(-dlog[h]));
    const float l2lam = log2f(lam);
    const int t = threadIdx.x;
    const int tx = t & 15, ty = t >> 4;
    const int row0 = b * TT + c * QC;
    const size_t gbase = (size_t)row0 * CC + h * DD;

    float acc[8][8] = {};

    for (int j0 = 0; j0 < QC; j0 += 16) {
        __syncthreads();
        {
            const int r = t >> 4, c8 = (t & 15) * 8;
            uint4 kraw = *(const uint4*)(kb + gbase + (size_t)(j0 + r) * CC + c8);
            uint4 vraw = *(const uint4*)(vb + gbase + (size_t)(j0 + r) * CC + c8);
            const u16* kp = (const u16*)&kraw;
            const u16* vp = (const u16*)&vraw;
            const float w = exp2f((float)(j0 + r) * l2lam);
            const float rk = 1.f / fmaxf(sqrtf(norms_k[row0 + j0 + r]), EPS);
            *(float4*)&ksA[r][c8]     = make_float4(bu2f(kp[0]) * rk, bu2f(kp[1]) * rk, bu2f(kp[2]) * rk, bu2f(kp[3]) * rk);
            *(float4*)&ksA[r][c8 + 4] = make_float4(bu2f(kp[4]) * rk, bu2f(kp[5]) * rk, bu2f(kp[6]) * rk, bu2f(kp[7]) * rk);
            *(float4*)&vsA[r][c8]     = make_float4(bu2f(vp[0]) * w, bu2f(vp[1]) * w, bu2f(vp[2]) * w, bu2f(vp[3]) * w);
            *(float4*)&vsA[r][c8 + 4] = make_float4(bu2f(vp[4]) * w, bu2f(vp[5]) * w, bu2f(vp[6]) * w, bu2f(vp[7]) * w);
        }
        __syncthreads();
        #pragma unroll
        for (int jj = 0; jj < 16; ++jj) {
            float4 va0 = *(const float4*)&vsA[jj][ty * 8];
            float4 va1 = *(const float4*)&vsA[jj][ty * 8 + 4];
            float4 ka0 = *(const float4*)&ksA[jj][tx * 8];
            float4 ka1 = *(const float4*)&ksA[jj][tx * 8 + 4];
            float vd[8] = {va0.x, va0.y, va0.z, va0.w, va1.x, va1.y, va1.z, va1.w};
            float ke[8] = {ka0.x, ka0.y, ka0.z, ka0.w, ka1.x, ka1.y, ka1.z, ka1.w};
            #pragma unroll
            for (int a = 0; a < 8; ++a)
                #pragma unroll
                for (int d = 0; d < 8; ++d)
                    acc[a][d] = fmaf(vd[a], ke[d], acc[a][d]);
        }
    }
    u16* so = statesb + ((size_t)(bh * NCH + c) << 14);
    #pragma unroll
    for (int a = 0; a < 8; ++a) {
        u16 h8[8];
        #pragma unroll
        for (int d = 0; d < 8; ++d) h8[d] = f2bu(acc[a][d]);
        *(uint4*)(so + (size_t)(ty * 8 + a) * DD + tx * 8) = *(uint4*)h8;
    }
}

// ---------------------------------------------------------------------------
// suffix combine in place, software-pipelined (prefetch distance 1).
// ---------------------------------------------------------------------------
__global__ __launch_bounds__(256) void state_combine(
    const float* __restrict__ dlog, u16* __restrict__ statesb)
{
    const int bh = blockIdx.x >> 3, part = blockIdx.x & 7;
    const int h = bh & 3;
    const float lam = 1.f / (1.f + __expf(-dlog[h]));
    const float lamQ = exp2f((float)QC * log2f(lam));
    const int t = threadIdx.x;
    float run[8] = {};
    uint4* pbase = (uint4*)(statesb + ((size_t)(bh * NCH) << 14)) + part * 256 + t;
    uint4 cur = pbase[(size_t)(NCH - 1) * 2048];
    for (int c = NCH - 1; c >= 0; --c) {
        uint4 nxt = cur;
        if (c) nxt = pbase[(size_t)(c - 1) * 2048];   // prefetch overlaps below
        u16* hb = (u16*)&cur;
        uint4 outw;
        u16* ho = (u16*)&outw;
        #pragma unroll
        for (int i = 0; i < 8; ++i) {
            float tmp = bu2f(hb[i]);
            ho[i] = f2bu(run[i]);
            run[i] = fmaf(lamQ, run[i], tmp);
        }
        pbase[(size_t)c * 2048] = outw;
        cur = nxt;
    }
}

// ---------------------------------------------------------------------------
// fused MFMA attention (bf16 in, norm scales applied here):
// P[i][j] = (qraw_i . kraw_j) * decay * rsq_k[j]   (bf16 via LDS)
// out_i   = (P@V + lam^(QC-1-i) * qraw_i @ St^T) * rsq_q[i]
// ---------------------------------------------------------------------------
__global__ __launch_bounds__(256) void attention_fused(
    const u16* __restrict__ qb, const u16* __restrict__ kb,
    const u16* __restrict__ vb, const u16* __restrict__ statesb,
    const float* __restrict__ norms, const float* __restrict__ dlog,
    u16* __restrict__ retb)
{
    __shared__ __align__(16) u16 qs[QC][DD];
    __shared__ __align__(16) u16 ks[QC][DD];
    __shared__ __align__(16) u16 vsT[DD][SST];
    __shared__ __align__(16) u16 ss[QC][SST];
    __shared__ float rql[QC], rkl[QC];

    const int c = blockIdx.x, bh = blockIdx.y;
    const int b = bh >> 2, h = bh & 3;
    const float lam = 1.f / (1.f + __expf(-dlog[h]));
    const float l2lam = log2f(lam);
    const int t = threadIdx.x;
    const int row0 = b * TT + c * QC;
    const size_t base = (size_t)row0 * CC + h * DD;

    const int wave = t >> 6, lane = t & 63;
    const int quad = lane >> 4, l16 = lane & 15;
    const int r0 = wave * 16;

    // ---- stage q,k via global_load_lds ----
    {
        const int lrow = lane >> 4;
        const int lcol = (lane & 15) * 8;
        #pragma unroll
        for (int u = 0; u < 4; ++u) {
            const int r = wave * 16 + u * 4;
            gl_lds16(qb + base + (size_t)(r + lrow) * CC + lcol, &qs[r][0]);
            gl_lds16(kb + base + (size_t)(r + lrow) * CC + lcol, &ks[r][0]);
        }
    }
    // ---- rsq scales ----
    if (t < QC)            rql[t]      = 1.f / fmaxf(sqrtf(norms[row0 + t]), EPS);
    else if (t < 2 * QC)   rkl[t - QC] = 1.f / fmaxf(sqrtf(norms[NROWS + row0 + t - QC]), EPS);
    // ---- stage v transposed -> vsT[d][j] ----
    {
        const int j2 = t & 31, d0 = (t >> 5) * 16;
        const u16* v0 = vb + base + (size_t)(2 * j2) * CC + d0;
        const u16* v1 = v0 + CC;
        uint4 a0 = *(const uint4*)v0;
        uint4 a1 = *(const uint4*)(v0 + 8);
        uint4 b0 = *(const uint4*)v1;
        uint4 b1 = *(const uint4*)(v1 + 8);
        const u16* ap0 = (const u16*)&a0; const u16* ap1 = (const u16*)&a1;
        const u16* bp0 = (const u16*)&b0; const u16* bp1 = (const u16*)&b1;
        #pragma unroll
        for (int i = 0; i < 8; ++i) {
            *(unsigned int*)&vsT[d0 + i][2 * j2] =
                (unsigned int)ap0[i] | ((unsigned int)bp0[i] << 16);
            *(unsigned int*)&vsT[d0 + 8 + i][2 * j2] =
                (unsigned int)ap1[i] | ((unsigned int)bp1[i] << 16);
        }
    }
    __syncthreads();   // the only barrier

    bf16x8 aq[4];
    #pragma unroll
    for (int kq = 0; kq < 4; ++kq)
        aq[kq] = *(const bf16x8*)&qs[r0 + l16][kq * 32 + quad * 8];

    // ---- scores ----
    f32x4 accs[4];
    #pragma unroll
    for (int nt = 0; nt < 4; ++nt) accs[nt] = (f32x4){0.f, 0.f, 0.f, 0.f};
    #pragma unroll
    for (int nt = 0; nt < 4; ++nt)
        #pragma unroll
        for (int kq = 0; kq < 4; ++kq) {
            bf16x8 bk = *(const bf16x8*)&ks[nt * 16 + l16][kq * 32 + quad * 8];
            accs[nt] = __builtin_amdgcn_mfma_f32_16x16x32_bf16(aq[kq], bk, accs[nt], 0, 0, 0);
        }

    // ---- decay + mask + k-norm -> P ----
    #pragma unroll
    for (int nt = 0; nt < 4; ++nt) {
        const int j = nt * 16 + l16;
        const float rkj = rkl[j];
        #pragma unroll
        for (int rr = 0; rr < 4; ++rr) {
            const int i = r0 + quad * 4 + rr;
            const int di = j - i;
            float p = (di > 0) ? accs[nt][rr] * exp2f((float)(di - 1) * l2lam) * rkj : 0.f;
            ss[i][j] = f2bu(p);
        }
    }

    // ---- cross: q @ St^T ----
    const u16* sb = statesb + ((size_t)(bh * NCH + c) << 14);
    f32x4 accc[8];
    #pragma unroll
    for (int nt = 0; nt < 8; ++nt) accc[nt] = (f32x4){0.f, 0.f, 0.f, 0.f};
    #pragma unroll
    for (int nt = 0; nt < 8; ++nt)
        #pragma unroll
        for (int kq = 0; kq < 4; ++kq) {
            bf16x8 bs_ = *(const bf16x8*)(sb + (size_t)(nt * 16 + l16) * DD + kq * 32 + quad * 8);
            accc[nt] = __builtin_amdgcn_mfma_f32_16x16x32_bf16(aq[kq], bs_, accc[nt], 0, 0, 0);
        }

    // ---- P @ V ----
    bf16x8 ap[2];
    #pragma unroll
    for (int kj = 0; kj < 2; ++kj)
        ap[kj] = *(const bf16x8*)&ss[r0 + l16][kj * 32 + quad * 8];
    f32x4 accd[8];
    #pragma unroll
    for (int nt = 0; nt < 8; ++nt) accd[nt] = (f32x4){0.f, 0.f, 0.f, 0.f};
    #pragma unroll
    for (int nt = 0; nt < 8; ++nt)
        #pragma unroll
        for (int kj = 0; kj < 2; ++kj) {
            bf16x8 bv = *(const bf16x8*)&vsT[nt * 16 + l16][kj * 32 + quad * 8];
            accd[nt] = __builtin_amdgcn_mfma_f32_16x16x32_bf16(ap[kj], bv, accd[nt], 0, 0, 0);
        }

    // ---- combine + q-norm + bf16 store ----
    u16* rb = retb + (size_t)row0 * CC + h * DD;
    #pragma unroll
    for (int rr = 0; rr < 4; ++rr) {
        const int ii = r0 + quad * 4 + rr;
        const float wrow = exp2f((float)(QC - 1 - ii) * l2lam);
        const float rq = rql[ii];
        #pragma unroll
        for (int nt = 0; nt < 8; ++nt) {
            float val = (accd[nt][rr] + wrow * accc[nt][rr]) * rq;
            rb[(size_t)ii * CC + nt * 16 + l16] = f2bu(val);
        }
    }
}

// ---------------------------------------------------------------------------
extern "C" void kernel_launch(void* const* d_in, const int* in_sizes, int n_in,
                              void* d_out, int out_size, void* d_ws, size_t ws_size,
                              hipStream_t stream) {
    const float* x         = (const float*)d_in[0];
    const float* basis     = (const float*)d_in[1];
    const float* qw        = (const float*)d_in[2];
    const float* kw        = (const float*)d_in[3];
    const float* v_coeffs  = (const float*)d_in[4];
    const float* o_coeffs  = (const float*)d_in[5];
    const float* dlog      = (const float*)d_in[6];
    const float* out_scale = (const float*)d_in[7];
    float* out             = (float*)d_out;

    u16* p = (u16*)d_ws;
    u16* qb      = p;                                   // 8192*512 bf16
    u16* kb      = qb + (size_t)NROWS * CC;
    u16* vb      = kb + (size_t)NROWS * CC;
    u16* statesb = vb + (size_t)NROWS * CC;             // 16*32*16384 bf16
    u16* xb      = statesb + (size_t)BB * HH * NCH * DD * DD;
    u16* retb    = xb;                                  // alias: xb dead after gemm_qkv
    u16* wcat    = xb + (size_t)NROWS * CC;             // 3 x 512x512 bf16
    u16* o_ws    = wcat + 3 * (size_t)VV * CC;
    float* norms = (float*)(o_ws + (size_t)VV * CC);    // 2 x 8192 fp32 (q, k)
    u16* bab     = (u16*)(norms + 2 * NROWS);           // 512*128 bf16
    u16* vcb     = bab + (size_t)VV * NB2;
    u16* ocb     = vcb + (size_t)VV * NB2;

    // 1. casts / transposes / norm-zero in one launch
    prep_all<<<PREP_CVT + PREP_TR + 3 * PREP_CB + PREP_Z, 256, 0, stream>>>(
        x, qw, kw, basis, v_coeffs, o_coeffs, out_scale,
        xb, wcat, wcat + (size_t)VV * CC, bab, vcb, ocb, norms);
    // 2. weight GEMMs via MFMA (v_wT -> wcat sec 2, o_ws)
    gemm_w<<<dim3(8, 4), 256, 0, stream>>>(bab, vcb, ocb,
                                           wcat + 2 * (size_t)VV * CC, o_ws);
    // 3. merged q/k/v projection (bf16 out) + fused row sumsq
    gemm_qkv<<<dim3(12, NROWS / 128), 256, 0, stream>>>(xb, wcat, qb, kb, vb, norms);
    // 4. chunked linear attention (all-MFMA; norms applied downstream)
    state_local  <<<dim3(NCH, BB * HH), 256, 0, stream>>>(kb, vb, norms + NROWS,
                                                          dlog, statesb);
    state_combine<<<BB * HH * 8, 256, 0, stream>>>(dlog, statesb);
    attention_fused<<<dim3(NCH, BB * HH), 256, 0, stream>>>(qb, kb, vb, statesb,
                                                            norms, dlog, retb);
    // 5. output projection (o_ws includes out_scale), fp32 out
    gemm_out<<<dim3(CC / 128, NROWS / 128), 256, 0, stream>>>(retb, o_ws, out);
}

// Round 11
// 168.932 us; speedup vs baseline: 1.3424x; 1.0750x over previous
//
#include <hip/hip_runtime.h>
#include <hip/hip_bf16.h>

// Problem constants (fixed by setup_inputs)
#define BB 4
#define TT 2048
#define VV 512
#define CC 512
#define HH 4
#define DD 128
#define NB2 128          // 2*NB
#define NROWS (BB*TT)    // 8192
#define QC 64            // linear-attention chunk length
#define NCH (TT/QC)      // 32 chunks per sequence
#define SST 66           // padded LDS stride (ushorts)
#define EPS 1e-12f

typedef __attribute__((ext_vector_type(8))) short bf16x8;
typedef __attribute__((ext_vector_type(4))) float f32x4;
typedef unsigned short u16;

__device__ __forceinline__ void gl_lds16(const void* g, void* l) {
    __builtin_amdgcn_global_load_lds(
        (const __attribute__((address_space(1))) unsigned int*)g,
        (__attribute__((address_space(3))) unsigned int*)l, 16, 0, 0);
}
__device__ __forceinline__ u16 f2bu(float x) {
    __hip_bfloat16 h = __float2bfloat16(x);
    return *reinterpret_cast<u16*>(&h);
}
__device__ __forceinline__ float bu2f(u16 u) {
    __hip_bfloat16 h = *reinterpret_cast<__hip_bfloat16*>(&u);
    return __bfloat162float(h);
}

// ---------------------------------------------------------------------------
// prep_all: (a) x->bf16 cast, (b) qw/kw transpose+cast, (c) basis/v_coeffs/
// o_coeffs*scale -> bf16 casts, (d) zero norms. Branch by blockIdx range.
// ---------------------------------------------------------------------------
#define PREP_CVT   4096                  // NROWS*CC/4/256 float4-blocks
#define PREP_TR    512                   // 256 32x32 tiles x 2 inputs
#define PREP_CB    64                    // 512*128 floats / (256*4)
#define PREP_Z     16                    // 16384 floats / (256*4)
__global__ __launch_bounds__(256) void prep_all(
    const float* __restrict__ x, const float* __restrict__ qw,
    const float* __restrict__ kw, const float* __restrict__ basis,
    const float* __restrict__ v_coeffs, const float* __restrict__ o_coeffs,
    const float* __restrict__ out_scale,
    u16* __restrict__ xb, u16* __restrict__ wq, u16* __restrict__ wk,
    u16* __restrict__ bab, u16* __restrict__ vcb, u16* __restrict__ ocb,
    float* __restrict__ norms)
{
    __shared__ float tile[32][33];
    const int bi = blockIdx.x, t = threadIdx.x;
    if (bi < PREP_CVT) {
        int i = bi * 256 + t;
        float4 v = ((const float4*)x)[i];
        u16 h[4] = {f2bu(v.x), f2bu(v.y), f2bu(v.z), f2bu(v.w)};
        ((uint2*)xb)[i] = *(uint2*)h;
    } else if (bi < PREP_CVT + PREP_TR) {
        int id = bi - PREP_CVT;
        const int z = id >> 8; id &= 255;
        const float* in = z ? kw : qw;
        u16* outT = z ? wk : wq;
        const int bx = (id & 15) * 32, by = (id >> 4) * 32;
        const int tx = t & 31, ty = t >> 5;
        #pragma unroll
        for (int r = 0; r < 32; r += 8)
            tile[ty + r][tx] = in[(size_t)(by + ty + r) * CC + bx + tx];
        __syncthreads();
        #pragma unroll
        for (int r = 0; r < 32; r += 8)
            outT[(size_t)(bx + ty + r) * VV + by + tx] = f2bu(tile[tx][ty + r]);
    } else if (bi < PREP_CVT + PREP_TR + 3 * PREP_CB) {
        int id = bi - PREP_CVT - PREP_TR;
        const int which = id / PREP_CB;        // 0=basis 1=v_coeffs 2=o_coeffs
        int i = (id - which * PREP_CB) * 256 + t;
        const float* src = which == 0 ? basis : (which == 1 ? v_coeffs : o_coeffs);
        u16* dst = which == 0 ? bab : (which == 1 ? vcb : ocb);
        const float sc = which == 2 ? out_scale[0] : 1.f;
        float4 v = ((const float4*)src)[i];
        u16 h[4] = {f2bu(v.x * sc), f2bu(v.y * sc), f2bu(v.z * sc), f2bu(v.w * sc)};
        ((uint2*)dst)[i] = *(uint2*)h;
    } else {
        int idx = (bi - PREP_CVT - PREP_TR - 3 * PREP_CB) * 256 + t;
        ((float4*)norms)[idx] = make_float4(0.f, 0.f, 0.f, 0.f);
    }
}

// ---------------------------------------------------------------------------
// bf16 MFMA GEMM body, double-buffered LDS, 128x128 tile, BK=32.
// Slot map: slot = row*4 + j, stored chunk c = (j - (row>>1)) & 3 (coalesced
// staging + conflict-free ds_read_b128). Optional fused row-sumsq.
// ---------------------------------------------------------------------------
template <bool BF16OUT, bool NORMS>
__device__ __forceinline__ void gemm_body(
    const u16* __restrict__ A, const u16* __restrict__ Bt,
    void* __restrict__ Cp, int M, int N, int K, int m0, int n0,
    u16* __restrict__ As, u16* __restrict__ Bs, float* __restrict__ normp)
{
    const int t = threadIdx.x;
    const int wave = t >> 6, lane = t & 63;
    const int qq = lane >> 4, l16 = lane & 15;
    const int wm = (wave >> 1) * 64, wn = (wave & 1) * 64;

    const int s0 = wave * 128 + lane, s1 = s0 + 64;
    const int r0_ = s0 >> 2, c0_ = ((s0 & 3) - (r0_ >> 1)) & 3;
    const int r1_ = s1 >> 2, c1_ = ((s1 & 3) - (r1_ >> 1)) & 3;
    const u16* ga0 = A  + (size_t)(m0 + r0_) * K + c0_ * 8;
    const u16* ga1 = A  + (size_t)(m0 + r1_) * K + c1_ * 8;
    const u16* gb0 = Bt + (size_t)(n0 + r0_) * K + c0_ * 8;
    const u16* gb1 = Bt + (size_t)(n0 + r1_) * K + c1_ * 8;
    const int lo0 = (wave * 128) * 8, lo1 = (wave * 128 + 64) * 8;

    gl_lds16(ga0, As + lo0);
    gl_lds16(ga1, As + lo1);
    gl_lds16(gb0, Bs + lo0);
    gl_lds16(gb1, Bs + lo1);

    f32x4 acc[4][4];
    #pragma unroll
    for (int i = 0; i < 4; ++i)
        #pragma unroll
        for (int j = 0; j < 4; ++j) acc[i][j] = (f32x4){0.f, 0.f, 0.f, 0.f};

    int ib = 0;
    for (int k0 = 0; k0 < K; k0 += 32, ib ^= 1) {
        __syncthreads();
        if (k0 + 32 < K) {
            const int off = (ib ^ 1) * 4096;
            gl_lds16(ga0 + k0 + 32, As + off + lo0);
            gl_lds16(ga1 + k0 + 32, As + off + lo1);
            gl_lds16(gb0 + k0 + 32, Bs + off + lo0);
            gl_lds16(gb1 + k0 + 32, Bs + off + lo1);
        }
        const u16* Ac = As + ib * 4096;
        const u16* Bc = Bs + ib * 4096;
        bf16x8 af[4], bfr[4];
        #pragma unroll
        for (int mt = 0; mt < 4; ++mt) {
            const int r = wm + mt * 16 + l16;
            af[mt] = *(const bf16x8*)&Ac[(r * 4 + ((qq + (r >> 1)) & 3)) * 8];
        }
        #pragma unroll
        for (int nt = 0; nt < 4; ++nt) {
            const int r = wn + nt * 16 + l16;
            bfr[nt] = *(const bf16x8*)&Bc[(r * 4 + ((qq + (r >> 1)) & 3)) * 8];
        }
        #pragma unroll
        for (int mt = 0; mt < 4; ++mt)
            #pragma unroll
            for (int nt = 0; nt < 4; ++nt)
                acc[mt][nt] = __builtin_amdgcn_mfma_f32_16x16x32_bf16(
                    af[mt], bfr[nt], acc[mt][nt], 0, 0, 0);
    }
    // C/D layout: col = lane&15, row = (lane>>4)*4 + reg
    #pragma unroll
    for (int mt = 0; mt < 4; ++mt)
        #pragma unroll
        for (int r = 0; r < 4; ++r) {
            int grow = m0 + wm + mt * 16 + qq * 4 + r;
            #pragma unroll
            for (int nt = 0; nt < 4; ++nt) {
                int gcol = n0 + wn + nt * 16 + l16;
                if (BF16OUT)
                    ((u16*)Cp)[(size_t)grow * N + gcol] = f2bu(acc[mt][nt][r]);
                else
                    ((float*)Cp)[(size_t)grow * N + gcol] = acc[mt][nt][r];
            }
        }
    if (NORMS && normp) {
        #pragma unroll
        for (int mt = 0; mt < 4; ++mt)
            #pragma unroll
            for (int r = 0; r < 4; ++r) {
                float s = 0.f;
                #pragma unroll
                for (int nt = 0; nt < 4; ++nt) {
                    float v = acc[mt][nt][r];
                    s = fmaf(v, v, s);
                }
                s += __shfl_xor(s, 1, 64);
                s += __shfl_xor(s, 2, 64);
                s += __shfl_xor(s, 4, 64);
                s += __shfl_xor(s, 8, 64);
                if (l16 == 0)
                    atomicAdd(&normp[m0 + wm + mt * 16 + qq * 4 + r], s);
            }
    }
}

// weight GEMMs via MFMA
__global__ __launch_bounds__(256) void gemm_w(
    const u16* __restrict__ bab, const u16* __restrict__ vcb,
    const u16* __restrict__ ocb, u16* __restrict__ v_wT, u16* __restrict__ o_ws)
{
    __shared__ __align__(16) u16 As[8192];
    __shared__ __align__(16) u16 Bs[8192];
    const int sec = blockIdx.x >> 2;
    const u16* A  = sec ? bab : vcb;
    const u16* Bt = sec ? ocb : bab;
    u16* C = sec ? o_ws : v_wT;
    gemm_body<true, false>(A, Bt, C, 512, 512, NB2,
                           blockIdx.y * 128, (blockIdx.x & 3) * 128, As, Bs, nullptr);
}

// merged q/k/v projection; sections 0/1 also accumulate row sumsq
__global__ __launch_bounds__(256) void gemm_qkv(
    const u16* __restrict__ xb, const u16* __restrict__ wcat,
    u16* __restrict__ qo, u16* __restrict__ ko, u16* __restrict__ vo,
    float* __restrict__ norms)
{
    __shared__ __align__(16) u16 As[8192];
    __shared__ __align__(16) u16 Bs[8192];
    const int sec = blockIdx.x >> 2;
    u16* outp = sec == 0 ? qo : (sec == 1 ? ko : vo);
    float* np = sec == 0 ? norms : (sec == 1 ? norms + NROWS : nullptr);
    gemm_body<true, true>(xb, wcat + (size_t)sec * VV * CC, outp,
                          NROWS, CC, VV, blockIdx.y * 128, (blockIdx.x & 3) * 128,
                          As, Bs, np);
}

// ---------------------------------------------------------------------------
// output projection, 64x128 tile -> 512 blocks (2/CU vs 1/CU at 128x128).
// ---------------------------------------------------------------------------
__global__ __launch_bounds__(256) void gemm_out64(
    const u16* __restrict__ A, const u16* __restrict__ Bt, float* __restrict__ C)
{
    __shared__ __align__(16) u16 As[4096];   // 2 x (64 rows x 32k)
    __shared__ __align__(16) u16 Bs[8192];   // 2 x (128 rows x 32k)
    const int t = threadIdx.x;
    const int wave = t >> 6, lane = t & 63;
    const int qq = lane >> 4, l16 = lane & 15;
    const int m0 = blockIdx.y * 64, n0 = blockIdx.x * 128;
    const int wm = (wave >> 1) * 32, wn = (wave & 1) * 64;
    const int N = VV, K = CC;

    const int sA = wave * 64 + lane;
    const int rA = sA >> 2, cA = ((sA & 3) - (rA >> 1)) & 3;
    const int sB0 = wave * 128 + lane, sB1 = sB0 + 64;
    const int rB0 = sB0 >> 2, cB0 = ((sB0 & 3) - (rB0 >> 1)) & 3;
    const int rB1 = sB1 >> 2, cB1 = ((sB1 & 3) - (rB1 >> 1)) & 3;
    const u16* ga  = A  + (size_t)(m0 + rA) * K + cA * 8;
    const u16* gb0 = Bt + (size_t)(n0 + rB0) * K + cB0 * 8;
    const u16* gb1 = Bt + (size_t)(n0 + rB1) * K + cB1 * 8;
    const int loA = wave * 512, loB0 = wave * 1024, loB1 = wave * 1024 + 512;

    gl_lds16(ga, As + loA);
    gl_lds16(gb0, Bs + loB0);
    gl_lds16(gb1, Bs + loB1);

    f32x4 acc[2][4];
    #pragma unroll
    for (int i = 0; i < 2; ++i)
        #pragma unroll
        for (int j = 0; j < 4; ++j) acc[i][j] = (f32x4){0.f, 0.f, 0.f, 0.f};

    int ib = 0;
    for (int k0 = 0; k0 < K; k0 += 32, ib ^= 1) {
        __syncthreads();
        if (k0 + 32 < K) {
            gl_lds16(ga + k0 + 32,  As + (ib ^ 1) * 2048 + loA);
            gl_lds16(gb0 + k0 + 32, Bs + (ib ^ 1) * 4096 + loB0);
            gl_lds16(gb1 + k0 + 32, Bs + (ib ^ 1) * 4096 + loB1);
        }
        const u16* Ac = As + ib * 2048;
        const u16* Bc = Bs + ib * 4096;
        bf16x8 af[2], bfr[4];
        #pragma unroll
        for (int mt = 0; mt < 2; ++mt) {
            const int r = wm + mt * 16 + l16;
            af[mt] = *(const bf16x8*)&Ac[(r * 4 + ((qq + (r >> 1)) & 3)) * 8];
        }
        #pragma unroll
        for (int nt = 0; nt < 4; ++nt) {
            const int r = wn + nt * 16 + l16;
            bfr[nt] = *(const bf16x8*)&Bc[(r * 4 + ((qq + (r >> 1)) & 3)) * 8];
        }
        #pragma unroll
        for (int mt = 0; mt < 2; ++mt)
            #pragma unroll
            for (int nt = 0; nt < 4; ++nt)
                acc[mt][nt] = __builtin_amdgcn_mfma_f32_16x16x32_bf16(
                    af[mt], bfr[nt], acc[mt][nt], 0, 0, 0);
    }
    #pragma unroll
    for (int mt = 0; mt < 2; ++mt)
        #pragma unroll
        for (int r = 0; r < 4; ++r) {
            int grow = m0 + wm + mt * 16 + qq * 4 + r;
            #pragma unroll
            for (int nt = 0; nt < 4; ++nt)
                C[(size_t)grow * N + n0 + wn + nt * 16 + l16] = acc[mt][nt][r];
        }
}

// ---------------------------------------------------------------------------
// per-chunk local states via MFMA (was VALU outer-product):
// St[d][e] = sum_j (v[j][d]*lam^j) * (k[j][e]*rk[j]), bf16 out.
// vT/kT staged transposed with SST padding (conflict-free), one barrier.
// ---------------------------------------------------------------------------
__global__ __launch_bounds__(256) void state_local(
    const u16* __restrict__ kb, const u16* __restrict__ vb,
    const float* __restrict__ norms_k, const float* __restrict__ dlog,
    u16* __restrict__ statesb)
{
    __shared__ __align__(16) u16 vT[DD][SST];
    __shared__ __align__(16) u16 kT[DD][SST];
    const int c = blockIdx.x, bh = blockIdx.y;
    const int b = bh >> 2, h = bh & 3;
    const float lam = 1.f / (1.f + __expf(-dlog[h]));
    const float l2lam = log2f(lam);
    const int t = threadIdx.x;
    const int row0 = b * TT + c * QC;
    const size_t gbase = (size_t)row0 * CC + h * DD;

    // stage transposed + scaled
    {
        const int j2 = t & 31, d0 = (t >> 5) * 16;
        const int jj0 = 2 * j2, jj1 = jj0 + 1;
        const float w0 = exp2f((float)jj0 * l2lam);
        const float w1 = exp2f((float)jj1 * l2lam);
        const float rk0 = 1.f / fmaxf(sqrtf(norms_k[row0 + jj0]), EPS);
        const float rk1 = 1.f / fmaxf(sqrtf(norms_k[row0 + jj1]), EPS);
        u16 k0a[16], k1a[16], v0a[16], v1a[16];
        const u16* k0p = kb + gbase + (size_t)jj0 * CC + d0;
        const u16* k1p = kb + gbase + (size_t)jj1 * CC + d0;
        const u16* v0p = vb + gbase + (size_t)jj0 * CC + d0;
        const u16* v1p = vb + gbase + (size_t)jj1 * CC + d0;
        *(uint4*)&k0a[0] = *(const uint4*)k0p; *(uint4*)&k0a[8] = *(const uint4*)(k0p + 8);
        *(uint4*)&k1a[0] = *(const uint4*)k1p; *(uint4*)&k1a[8] = *(const uint4*)(k1p + 8);
        *(uint4*)&v0a[0] = *(const uint4*)v0p; *(uint4*)&v0a[8] = *(const uint4*)(v0p + 8);
        *(uint4*)&v1a[0] = *(const uint4*)v1p; *(uint4*)&v1a[8] = *(const uint4*)(v1p + 8);
        #pragma unroll
        for (int i = 0; i < 16; ++i) {
            unsigned int kw = (unsigned int)f2bu(bu2f(k0a[i]) * rk0)
                            | ((unsigned int)f2bu(bu2f(k1a[i]) * rk1) << 16);
            *(unsigned int*)&kT[d0 + i][jj0] = kw;
            unsigned int vw = (unsigned int)f2bu(bu2f(v0a[i]) * w0)
                            | ((unsigned int)f2bu(bu2f(v1a[i]) * w1) << 16);
            *(unsigned int*)&vT[d0 + i][jj0] = vw;
        }
    }
    __syncthreads();

    const int wave = t >> 6, lane = t & 63;
    const int quad = lane >> 4, l16 = lane & 15;
    f32x4 acc[2][8];
    #pragma unroll
    for (int i = 0; i < 2; ++i)
        #pragma unroll
        for (int j = 0; j < 8; ++j) acc[i][j] = (f32x4){0.f, 0.f, 0.f, 0.f};

    #pragma unroll
    for (int s = 0; s < 2; ++s) {
        bf16x8 af[2];
        #pragma unroll
        for (int mt = 0; mt < 2; ++mt)
            af[mt] = *(const bf16x8*)&vT[wave * 32 + mt * 16 + l16][s * 32 + quad * 8];
        #pragma unroll
        for (int nt = 0; nt < 8; ++nt) {
            bf16x8 bk = *(const bf16x8*)&kT[nt * 16 + l16][s * 32 + quad * 8];
            #pragma unroll
            for (int mt = 0; mt < 2; ++mt)
                acc[mt][nt] = __builtin_amdgcn_mfma_f32_16x16x32_bf16(
                    af[mt], bk, acc[mt][nt], 0, 0, 0);
        }
    }
    u16* so = statesb + ((size_t)(bh * NCH + c) << 14);
    #pragma unroll
    for (int mt = 0; mt < 2; ++mt)
        #pragma unroll
        for (int rr = 0; rr < 4; ++rr) {
            const int d = wave * 32 + mt * 16 + quad * 4 + rr;
            #pragma unroll
            for (int nt = 0; nt < 8; ++nt)
                so[(size_t)d * DD + nt * 16 + l16] = f2bu(acc[mt][nt][rr]);
        }
}

// ---------------------------------------------------------------------------
// suffix combine in place, software-pipelined (prefetch distance 1).
// ---------------------------------------------------------------------------
__global__ __launch_bounds__(256) void state_combine(
    const float* __restrict__ dlog, u16* __restrict__ statesb)
{
    const int bh = blockIdx.x >> 3, part = blockIdx.x & 7;
    const int h = bh & 3;
    const float lam = 1.f / (1.f + __expf(-dlog[h]));
    const float lamQ = exp2f((float)QC * log2f(lam));
    const int t = threadIdx.x;
    float run[8] = {};
    uint4* pbase = (uint4*)(statesb + ((size_t)(bh * NCH) << 14)) + part * 256 + t;
    uint4 cur = pbase[(size_t)(NCH - 1) * 2048];
    for (int c = NCH - 1; c >= 0; --c) {
        uint4 nxt = cur;
        if (c) nxt = pbase[(size_t)(c - 1) * 2048];   // prefetch overlaps below
        u16* hb = (u16*)&cur;
        uint4 outw;
        u16* ho = (u16*)&outw;
        #pragma unroll
        for (int i = 0; i < 8; ++i) {
            float tmp = bu2f(hb[i]);
            ho[i] = f2bu(run[i]);
            run[i] = fmaf(lamQ, run[i], tmp);
        }
        pbase[(size_t)c * 2048] = outw;
        cur = nxt;
    }
}

// ---------------------------------------------------------------------------
// fused MFMA attention. Rotated-chunk LDS layout for q/k/St:
//   phys_chunk = (logical_chunk + row) & 15   (16B chunks, DD=16 chunks/row)
// -> conflict-free ds_read_b128 AND gl_lds-compatible (per-lane src permute).
// St staged into the dead qs/ks space via gl_lds, overlapped with P@V.
// ---------------------------------------------------------------------------
__global__ __launch_bounds__(256) void attention_fused(
    const u16* __restrict__ qb, const u16* __restrict__ kb,
    const u16* __restrict__ vb, const u16* __restrict__ statesb,
    const float* __restrict__ norms, const float* __restrict__ dlog,
    u16* __restrict__ retb)
{
    __shared__ __align__(16) u16 qks[2 * QC * DD];   // qs rows 0..63, ks 64..127; St later
    __shared__ __align__(16) u16 vsT[DD][SST];
    __shared__ __align__(16) u16 ss[QC][SST];
    __shared__ float rql[QC], rkl[QC];

    const int c = blockIdx.x, bh = blockIdx.y;
    const int b = bh >> 2, h = bh & 3;
    const float lam = 1.f / (1.f + __expf(-dlog[h]));
    const float l2lam = log2f(lam);
    const int t = threadIdx.x;
    const int row0 = b * TT + c * QC;
    const size_t base = (size_t)row0 * CC + h * DD;

    const int wave = t >> 6, lane = t & 63;
    const int quad = lane >> 4, l16 = lane & 15;
    const int r0 = wave * 16;

    // ---- stage q,k via gl_lds with rotated source chunks ----
    {
        const int lrow = lane >> 4, cch = lane & 15;
        #pragma unroll
        for (int u = 0; u < 4; ++u) {
            const int R = wave * 16 + u * 4;
            const int gr = R + lrow;
            const int cq = (cch - gr) & 15;
            gl_lds16(qb + base + (size_t)gr * CC + cq * 8, &qks[R * DD]);
            gl_lds16(kb + base + (size_t)gr * CC + cq * 8, &qks[(QC + R) * DD]);
        }
    }
    // ---- rsq scales ----
    if (t < QC)            rql[t]      = 1.f / fmaxf(sqrtf(norms[row0 + t]), EPS);
    else if (t < 2 * QC)   rkl[t - QC] = 1.f / fmaxf(sqrtf(norms[NROWS + row0 + t - QC]), EPS);
    // ---- stage v transposed -> vsT[d][j] ----
    {
        const int j2 = t & 31, d0 = (t >> 5) * 16;
        const u16* v0 = vb + base + (size_t)(2 * j2) * CC + d0;
        const u16* v1 = v0 + CC;
        uint4 a0 = *(const uint4*)v0;
        uint4 a1 = *(const uint4*)(v0 + 8);
        uint4 b0 = *(const uint4*)v1;
        uint4 b1 = *(const uint4*)(v1 + 8);
        const u16* ap0 = (const u16*)&a0; const u16* ap1 = (const u16*)&a1;
        const u16* bp0 = (const u16*)&b0; const u16* bp1 = (const u16*)&b1;
        #pragma unroll
        for (int i = 0; i < 8; ++i) {
            *(unsigned int*)&vsT[d0 + i][2 * j2] =
                (unsigned int)ap0[i] | ((unsigned int)bp0[i] << 16);
            *(unsigned int*)&vsT[d0 + 8 + i][2 * j2] =
                (unsigned int)ap1[i] | ((unsigned int)bp1[i] << 16);
        }
    }
    __syncthreads();   // barrier 1: q/k DMA + vsT/rs writes complete

    // A fragments (q rows r0+l16) — rotated chunk addressing
    bf16x8 aq[4];
    #pragma unroll
    for (int kq = 0; kq < 4; ++kq) {
        const int r = r0 + l16;
        aq[kq] = *(const bf16x8*)&qks[r * DD + ((kq * 4 + quad + r) & 15) * 8];
    }

    // ---- scores ----
    f32x4 accs[4];
    #pragma unroll
    for (int nt = 0; nt < 4; ++nt) accs[nt] = (f32x4){0.f, 0.f, 0.f, 0.f};
    #pragma unroll
    for (int nt = 0; nt < 4; ++nt)
        #pragma unroll
        for (int kq = 0; kq < 4; ++kq) {
            const int rk_ = nt * 16 + l16;
            bf16x8 bk = *(const bf16x8*)&qks[(QC + rk_) * DD + ((kq * 4 + quad + rk_) & 15) * 8];
            accs[nt] = __builtin_amdgcn_mfma_f32_16x16x32_bf16(aq[kq], bk, accs[nt], 0, 0, 0);
        }

    // ---- decay + mask + k-norm -> P ----
    #pragma unroll
    for (int nt = 0; nt < 4; ++nt) {
        const int j = nt * 16 + l16;
        const float rkj = rkl[j];
        #pragma unroll
        for (int rr = 0; rr < 4; ++rr) {
            const int i = r0 + quad * 4 + rr;
            const int di = j - i;
            float p = (di > 0) ? accs[nt][rr] * exp2f((float)(di - 1) * l2lam) * rkj : 0.f;
            ss[i][j] = f2bu(p);
        }
    }
    __syncthreads();   // barrier 2: all q/k LDS reads done -> safe to overwrite with St

    // ---- issue St DMA into qks (rotated), then do P@V while it flies ----
    const u16* sb = statesb + ((size_t)(bh * NCH + c) << 14);
    {
        const int drow = lane >> 4, cch = lane & 15;
        #pragma unroll
        for (int u = 0; u < 8; ++u) {
            const int D = wave * 32 + u * 4;
            const int gd = D + drow;
            const int cq = (cch - gd) & 15;
            gl_lds16(sb + (size_t)gd * DD + cq * 8, &qks[D * DD]);
        }
    }
    // P @ V (independent of St)
    bf16x8 ap[2];
    #pragma unroll
    for (int kj = 0; kj < 2; ++kj)
        ap[kj] = *(const bf16x8*)&ss[r0 + l16][kj * 32 + quad * 8];
    f32x4 accd[8];
    #pragma unroll
    for (int nt = 0; nt < 8; ++nt) accd[nt] = (f32x4){0.f, 0.f, 0.f, 0.f};
    #pragma unroll
    for (int nt = 0; nt < 8; ++nt)
        #pragma unroll
        for (int kj = 0; kj < 2; ++kj) {
            bf16x8 bv = *(const bf16x8*)&vsT[nt * 16 + l16][kj * 32 + quad * 8];
            accd[nt] = __builtin_amdgcn_mfma_f32_16x16x32_bf16(ap[kj], bv, accd[nt], 0, 0, 0);
        }
    __syncthreads();   // barrier 3: St landed

    // ---- cross: q @ St^T from LDS ----
    f32x4 accc[8];
    #pragma unroll
    for (int nt = 0; nt < 8; ++nt) accc[nt] = (f32x4){0.f, 0.f, 0.f, 0.f};
    #pragma unroll
    for (int nt = 0; nt < 8; ++nt)
        #pragma unroll
        for (int kq = 0; kq < 4; ++kq) {
            const int d = nt * 16 + l16;
            bf16x8 bs_ = *(const bf16x8*)&qks[d * DD + ((kq * 4 + quad + d) & 15) * 8];
            accc[nt] = __builtin_amdgcn_mfma_f32_16x16x32_bf16(aq[kq], bs_, accc[nt], 0, 0, 0);
        }

    // ---- combine + q-norm + bf16 store ----
    u16* rb = retb + (size_t)row0 * CC + h * DD;
    #pragma unroll
    for (int rr = 0; rr < 4; ++rr) {
        const int ii = r0 + quad * 4 + rr;
        const float wrow = exp2f((float)(QC - 1 - ii) * l2lam);
        const float rq = rql[ii];
        #pragma unroll
        for (int nt = 0; nt < 8; ++nt) {
            float val = (accd[nt][rr] + wrow * accc[nt][rr]) * rq;
            rb[(size_t)ii * CC + nt * 16 + l16] = f2bu(val);
        }
    }
}

// ---------------------------------------------------------------------------
extern "C" void kernel_launch(void* const* d_in, const int* in_sizes, int n_in,
                              void* d_out, int out_size, void* d_ws, size_t ws_size,
                              hipStream_t stream) {
    const float* x         = (const float*)d_in[0];
    const float* basis     = (const float*)d_in[1];
    const float* qw        = (const float*)d_in[2];
    const float* kw        = (const float*)d_in[3];
    const float* v_coeffs  = (const float*)d_in[4];
    const float* o_coeffs  = (const float*)d_in[5];
    const float* dlog      = (const float*)d_in[6];
    const float* out_scale = (const float*)d_in[7];
    float* out             = (float*)d_out;

    u16* p = (u16*)d_ws;
    u16* qb      = p;                                   // 8192*512 bf16
    u16* kb      = qb + (size_t)NROWS * CC;
    u16* vb      = kb + (size_t)NROWS * CC;
    u16* statesb = vb + (size_t)NROWS * CC;             // 16*32*16384 bf16
    u16* xb      = statesb + (size_t)BB * HH * NCH * DD * DD;
    u16* retb    = xb;                                  // alias: xb dead after gemm_qkv
    u16* wcat    = xb + (size_t)NROWS * CC;             // 3 x 512x512 bf16
    u16* o_ws    = wcat + 3 * (size_t)VV * CC;
    float* norms = (float*)(o_ws + (size_t)VV * CC);    // 2 x 8192 fp32 (q, k)
    u16* bab     = (u16*)(norms + 2 * NROWS);           // 512*128 bf16
    u16* vcb     = bab + (size_t)VV * NB2;
    u16* ocb     = vcb + (size_t)VV * NB2;

    // 1. casts / transposes / norm-zero in one launch
    prep_all<<<PREP_CVT + PREP_TR + 3 * PREP_CB + PREP_Z, 256, 0, stream>>>(
        x, qw, kw, basis, v_coeffs, o_coeffs, out_scale,
        xb, wcat, wcat + (size_t)VV * CC, bab, vcb, ocb, norms);
    // 2. weight GEMMs via MFMA (v_wT -> wcat sec 2, o_ws)
    gemm_w<<<dim3(8, 4), 256, 0, stream>>>(bab, vcb, ocb,
                                           wcat + 2 * (size_t)VV * CC, o_ws);
    // 3. merged q/k/v projection (bf16 out) + fused row sumsq
    gemm_qkv<<<dim3(12, NROWS / 128), 256, 0, stream>>>(xb, wcat, qb, kb, vb, norms);
    // 4. chunked linear attention (all-MFMA; norms applied downstream)
    state_local  <<<dim3(NCH, BB * HH), 256, 0, stream>>>(kb, vb, norms + NROWS,
                                                          dlog, statesb);
    state_combine<<<BB * HH * 8, 256, 0, stream>>>(dlog, statesb);
    attention_fused<<<dim3(NCH, BB * HH), 256, 0, stream>>>(qb, kb, vb, statesb,
                                                            norms, dlog, retb);
    // 5. output projection (o_ws includes out_scale), fp32 out
    gemm_out64<<<dim3(VV / 128, NROWS / 64), 256, 0, stream>>>(retb, o_ws, out);
}

// Round 12
// 168.616 us; speedup vs baseline: 1.3449x; 1.0019x over previous
//
#include <hip/hip_runtime.h>
#include <hip/hip_bf16.h>

// Problem constants (fixed by setup_inputs)
#define BB 4
#define TT 2048
#define VV 512
#define CC 512
#define HH 4
#define DD 128
#define NB2 128          // 2*NB
#define NROWS (BB*TT)    // 8192
#define QC 64            // linear-attention chunk length
#define NCH (TT/QC)      // 32 chunks per sequence
#define SST 66           // padded LDS stride (ushorts)
#define EPS 1e-12f

typedef __attribute__((ext_vector_type(8))) short bf16x8;
typedef __attribute__((ext_vector_type(4))) float f32x4;
typedef unsigned short u16;

__device__ __forceinline__ void gl_lds16(const void* g, void* l) {
    __builtin_amdgcn_global_load_lds(
        (const __attribute__((address_space(1))) unsigned int*)g,
        (__attribute__((address_space(3))) unsigned int*)l, 16, 0, 0);
}
__device__ __forceinline__ u16 f2bu(float x) {
    __hip_bfloat16 h = __float2bfloat16(x);
    return *reinterpret_cast<u16*>(&h);
}
__device__ __forceinline__ float bu2f(u16 u) {
    __hip_bfloat16 h = *reinterpret_cast<__hip_bfloat16*>(&u);
    return __bfloat162float(h);
}

// ---------------------------------------------------------------------------
// prep_all: (a) x->bf16 cast, (b) qw/kw transpose+cast, (c) basis/v_coeffs/
// o_coeffs*scale -> bf16 casts, (d) zero norms. Branch by blockIdx range.
// ---------------------------------------------------------------------------
#define PREP_CVT   4096                  // NROWS*CC/4/256 float4-blocks
#define PREP_TR    512                   // 256 32x32 tiles x 2 inputs
#define PREP_CB    64                    // 512*128 floats / (256*4)
#define PREP_Z     16                    // 16384 floats / (256*4)
__global__ __launch_bounds__(256) void prep_all(
    const float* __restrict__ x, const float* __restrict__ qw,
    const float* __restrict__ kw, const float* __restrict__ basis,
    const float* __restrict__ v_coeffs, const float* __restrict__ o_coeffs,
    const float* __restrict__ out_scale,
    u16* __restrict__ xb, u16* __restrict__ wq, u16* __restrict__ wk,
    u16* __restrict__ bab, u16* __restrict__ vcb, u16* __restrict__ ocb,
    float* __restrict__ norms)
{
    __shared__ float tile[32][33];
    const int bi = blockIdx.x, t = threadIdx.x;
    if (bi < PREP_CVT) {
        int i = bi * 256 + t;
        float4 v = ((const float4*)x)[i];
        u16 h[4] = {f2bu(v.x), f2bu(v.y), f2bu(v.z), f2bu(v.w)};
        ((uint2*)xb)[i] = *(uint2*)h;
    } else if (bi < PREP_CVT + PREP_TR) {
        int id = bi - PREP_CVT;
        const int z = id >> 8; id &= 255;
        const float* in = z ? kw : qw;
        u16* outT = z ? wk : wq;
        const int bx = (id & 15) * 32, by = (id >> 4) * 32;
        const int tx = t & 31, ty = t >> 5;
        #pragma unroll
        for (int r = 0; r < 32; r += 8)
            tile[ty + r][tx] = in[(size_t)(by + ty + r) * CC + bx + tx];
        __syncthreads();
        #pragma unroll
        for (int r = 0; r < 32; r += 8)
            outT[(size_t)(bx + ty + r) * VV + by + tx] = f2bu(tile[tx][ty + r]);
    } else if (bi < PREP_CVT + PREP_TR + 3 * PREP_CB) {
        int id = bi - PREP_CVT - PREP_TR;
        const int which = id / PREP_CB;        // 0=basis 1=v_coeffs 2=o_coeffs
        int i = (id - which * PREP_CB) * 256 + t;
        const float* src = which == 0 ? basis : (which == 1 ? v_coeffs : o_coeffs);
        u16* dst = which == 0 ? bab : (which == 1 ? vcb : ocb);
        const float sc = which == 2 ? out_scale[0] : 1.f;
        float4 v = ((const float4*)src)[i];
        u16 h[4] = {f2bu(v.x * sc), f2bu(v.y * sc), f2bu(v.z * sc), f2bu(v.w * sc)};
        ((uint2*)dst)[i] = *(uint2*)h;
    } else {
        int idx = (bi - PREP_CVT - PREP_TR - 3 * PREP_CB) * 256 + t;
        ((float4*)norms)[idx] = make_float4(0.f, 0.f, 0.f, 0.f);
    }
}

// ---------------------------------------------------------------------------
// bf16 MFMA GEMM body (for gemm_w), double-buffered, 128x128 tile, BK=32.
// Slot map: slot = row*4 + j, stored chunk c = (j - (row>>1)) & 3.
// ---------------------------------------------------------------------------
__device__ __forceinline__ void gemm_body(
    const u16* __restrict__ A, const u16* __restrict__ Bt,
    u16* __restrict__ Cp, int N, int K, int m0, int n0,
    u16* __restrict__ As, u16* __restrict__ Bs)
{
    const int t = threadIdx.x;
    const int wave = t >> 6, lane = t & 63;
    const int qq = lane >> 4, l16 = lane & 15;
    const int wm = (wave >> 1) * 64, wn = (wave & 1) * 64;

    const int s0 = wave * 128 + lane, s1 = s0 + 64;
    const int r0_ = s0 >> 2, c0_ = ((s0 & 3) - (r0_ >> 1)) & 3;
    const int r1_ = s1 >> 2, c1_ = ((s1 & 3) - (r1_ >> 1)) & 3;
    const u16* ga0 = A  + (size_t)(m0 + r0_) * K + c0_ * 8;
    const u16* ga1 = A  + (size_t)(m0 + r1_) * K + c1_ * 8;
    const u16* gb0 = Bt + (size_t)(n0 + r0_) * K + c0_ * 8;
    const u16* gb1 = Bt + (size_t)(n0 + r1_) * K + c1_ * 8;
    const int lo0 = (wave * 128) * 8, lo1 = (wave * 128 + 64) * 8;

    gl_lds16(ga0, As + lo0);
    gl_lds16(ga1, As + lo1);
    gl_lds16(gb0, Bs + lo0);
    gl_lds16(gb1, Bs + lo1);

    f32x4 acc[4][4];
    #pragma unroll
    for (int i = 0; i < 4; ++i)
        #pragma unroll
        for (int j = 0; j < 4; ++j) acc[i][j] = (f32x4){0.f, 0.f, 0.f, 0.f};

    int ib = 0;
    for (int k0 = 0; k0 < K; k0 += 32, ib ^= 1) {
        __syncthreads();
        if (k0 + 32 < K) {
            const int off = (ib ^ 1) * 4096;
            gl_lds16(ga0 + k0 + 32, As + off + lo0);
            gl_lds16(ga1 + k0 + 32, As + off + lo1);
            gl_lds16(gb0 + k0 + 32, Bs + off + lo0);
            gl_lds16(gb1 + k0 + 32, Bs + off + lo1);
        }
        const u16* Ac = As + ib * 4096;
        const u16* Bc = Bs + ib * 4096;
        bf16x8 af[4], bfr[4];
        #pragma unroll
        for (int mt = 0; mt < 4; ++mt) {
            const int r = wm + mt * 16 + l16;
            af[mt] = *(const bf16x8*)&Ac[(r * 4 + ((qq + (r >> 1)) & 3)) * 8];
        }
        #pragma unroll
        for (int nt = 0; nt < 4; ++nt) {
            const int r = wn + nt * 16 + l16;
            bfr[nt] = *(const bf16x8*)&Bc[(r * 4 + ((qq + (r >> 1)) & 3)) * 8];
        }
        #pragma unroll
        for (int mt = 0; mt < 4; ++mt)
            #pragma unroll
            for (int nt = 0; nt < 4; ++nt)
                acc[mt][nt] = __builtin_amdgcn_mfma_f32_16x16x32_bf16(
                    af[mt], bfr[nt], acc[mt][nt], 0, 0, 0);
    }
    #pragma unroll
    for (int mt = 0; mt < 4; ++mt)
        #pragma unroll
        for (int r = 0; r < 4; ++r) {
            int grow = m0 + wm + mt * 16 + qq * 4 + r;
            #pragma unroll
            for (int nt = 0; nt < 4; ++nt)
                Cp[(size_t)grow * N + n0 + wn + nt * 16 + l16] = f2bu(acc[mt][nt][r]);
        }
}

// weight GEMMs via MFMA
__global__ __launch_bounds__(256) void gemm_w(
    const u16* __restrict__ bab, const u16* __restrict__ vcb,
    const u16* __restrict__ ocb, u16* __restrict__ v_wT, u16* __restrict__ o_ws)
{
    __shared__ __align__(16) u16 As[8192];
    __shared__ __align__(16) u16 Bs[8192];
    const int sec = blockIdx.x >> 2;
    const u16* A  = sec ? bab : vcb;
    const u16* Bt = sec ? ocb : bab;
    u16* C = sec ? o_ws : v_wT;
    gemm_body(A, Bt, C, 512, NB2, blockIdx.y * 128, (blockIdx.x & 3) * 128, As, Bs);
}

// ---------------------------------------------------------------------------
// FUSED q/k/v projection: one pass over x. Per K-step: stage A once (8KB) +
// 3 B-tiles (24KB), 48 MFMAs -> 1.5x arithmetic intensity per staged byte
// vs separate GEMMs, and x is fetched once from HBM instead of 3x.
// Grid (4 n-tiles, 64 m-tiles) = 256 blocks. LDS 64KB. acc[3][4][4] ~192 VGPR.
// ---------------------------------------------------------------------------
__global__ __launch_bounds__(256, 1) void gemm_qkv_fused(
    const u16* __restrict__ xb, const u16* __restrict__ wcat,
    u16* __restrict__ qo, u16* __restrict__ ko, u16* __restrict__ vo,
    float* __restrict__ norms)
{
    __shared__ __align__(16) u16 As[2 * 4096];       // 16KB
    __shared__ __align__(16) u16 Bs[3 * 2 * 4096];   // 48KB  (sec-major, dbuf inner)
    const int t = threadIdx.x;
    const int wave = t >> 6, lane = t & 63;
    const int qq = lane >> 4, l16 = lane & 15;
    const int m0 = blockIdx.y * 128, n0 = blockIdx.x * 128;
    const int wm = (wave >> 1) * 64, wn = (wave & 1) * 64;
    const int K = VV;

    const int s0 = wave * 128 + lane, s1 = s0 + 64;
    const int r0_ = s0 >> 2, c0_ = ((s0 & 3) - (r0_ >> 1)) & 3;
    const int r1_ = s1 >> 2, c1_ = ((s1 & 3) - (r1_ >> 1)) & 3;
    const u16* ga0 = xb + (size_t)(m0 + r0_) * K + c0_ * 8;
    const u16* ga1 = xb + (size_t)(m0 + r1_) * K + c1_ * 8;
    const u16* gb0[3];
    const u16* gb1[3];
    #pragma unroll
    for (int sec = 0; sec < 3; ++sec) {
        gb0[sec] = wcat + (size_t)sec * VV * CC + (size_t)(n0 + r0_) * K + c0_ * 8;
        gb1[sec] = wcat + (size_t)sec * VV * CC + (size_t)(n0 + r1_) * K + c1_ * 8;
    }
    const int lo0 = (wave * 128) * 8, lo1 = lo0 + 512;

    // prologue -> buffer 0
    gl_lds16(ga0, As + lo0);
    gl_lds16(ga1, As + lo1);
    #pragma unroll
    for (int sec = 0; sec < 3; ++sec) {
        gl_lds16(gb0[sec], Bs + sec * 8192 + lo0);
        gl_lds16(gb1[sec], Bs + sec * 8192 + lo1);
    }

    f32x4 acc[3][4][4];
    #pragma unroll
    for (int s = 0; s < 3; ++s)
        #pragma unroll
        for (int i = 0; i < 4; ++i)
            #pragma unroll
            for (int j = 0; j < 4; ++j) acc[s][i][j] = (f32x4){0.f, 0.f, 0.f, 0.f};

    int ib = 0;
    for (int k0 = 0; k0 < K; k0 += 32, ib ^= 1) {
        __syncthreads();
        if (k0 + 32 < K) {
            const int off = (ib ^ 1) * 4096;
            gl_lds16(ga0 + k0 + 32, As + off + lo0);
            gl_lds16(ga1 + k0 + 32, As + off + lo1);
            #pragma unroll
            for (int sec = 0; sec < 3; ++sec) {
                gl_lds16(gb0[sec] + k0 + 32, Bs + sec * 8192 + off + lo0);
                gl_lds16(gb1[sec] + k0 + 32, Bs + sec * 8192 + off + lo1);
            }
        }
        const u16* Ac = As + ib * 4096;
        bf16x8 af[4];
        #pragma unroll
        for (int mt = 0; mt < 4; ++mt) {
            const int r = wm + mt * 16 + l16;
            af[mt] = *(const bf16x8*)&Ac[(r * 4 + ((qq + (r >> 1)) & 3)) * 8];
        }
        #pragma unroll
        for (int sec = 0; sec < 3; ++sec) {
            const u16* Bc = Bs + sec * 8192 + ib * 4096;
            bf16x8 bfr[4];
            #pragma unroll
            for (int nt = 0; nt < 4; ++nt) {
                const int r = wn + nt * 16 + l16;
                bfr[nt] = *(const bf16x8*)&Bc[(r * 4 + ((qq + (r >> 1)) & 3)) * 8];
            }
            #pragma unroll
            for (int mt = 0; mt < 4; ++mt)
                #pragma unroll
                for (int nt = 0; nt < 4; ++nt)
                    acc[sec][mt][nt] = __builtin_amdgcn_mfma_f32_16x16x32_bf16(
                        af[mt], bfr[nt], acc[sec][mt][nt], 0, 0, 0);
        }
    }
    // epilogue: bf16 stores + fused row-sumsq for q (sec 0) and k (sec 1)
    #pragma unroll
    for (int sec = 0; sec < 3; ++sec) {
        u16* outp = sec == 0 ? qo : (sec == 1 ? ko : vo);
        #pragma unroll
        for (int mt = 0; mt < 4; ++mt)
            #pragma unroll
            for (int r = 0; r < 4; ++r) {
                int grow = m0 + wm + mt * 16 + qq * 4 + r;
                #pragma unroll
                for (int nt = 0; nt < 4; ++nt)
                    outp[(size_t)grow * CC + n0 + wn + nt * 16 + l16] =
                        f2bu(acc[sec][mt][nt][r]);
            }
        if (sec < 2) {
            float* np = sec == 0 ? norms : norms + NROWS;
            #pragma unroll
            for (int mt = 0; mt < 4; ++mt)
                #pragma unroll
                for (int r = 0; r < 4; ++r) {
                    float s = 0.f;
                    #pragma unroll
                    for (int nt = 0; nt < 4; ++nt) {
                        float v = acc[sec][mt][nt][r];
                        s = fmaf(v, v, s);
                    }
                    s += __shfl_xor(s, 1, 64);
                    s += __shfl_xor(s, 2, 64);
                    s += __shfl_xor(s, 4, 64);
                    s += __shfl_xor(s, 8, 64);
                    if (l16 == 0)
                        atomicAdd(&np[m0 + wm + mt * 16 + qq * 4 + r], s);
                }
        }
    }
}

// ---------------------------------------------------------------------------
// output projection, 64x128 tile -> 512 blocks (2/CU).
// ---------------------------------------------------------------------------
__global__ __launch_bounds__(256) void gemm_out64(
    const u16* __restrict__ A, const u16* __restrict__ Bt, float* __restrict__ C)
{
    __shared__ __align__(16) u16 As[4096];
    __shared__ __align__(16) u16 Bs[8192];
    const int t = threadIdx.x;
    const int wave = t >> 6, lane = t & 63;
    const int qq = lane >> 4, l16 = lane & 15;
    const int m0 = blockIdx.y * 64, n0 = blockIdx.x * 128;
    const int wm = (wave >> 1) * 32, wn = (wave & 1) * 64;
    const int N = VV, K = CC;

    const int sA = wave * 64 + lane;
    const int rA = sA >> 2, cA = ((sA & 3) - (rA >> 1)) & 3;
    const int sB0 = wave * 128 + lane, sB1 = sB0 + 64;
    const int rB0 = sB0 >> 2, cB0 = ((sB0 & 3) - (rB0 >> 1)) & 3;
    const int rB1 = sB1 >> 2, cB1 = ((sB1 & 3) - (rB1 >> 1)) & 3;
    const u16* ga  = A  + (size_t)(m0 + rA) * K + cA * 8;
    const u16* gb0 = Bt + (size_t)(n0 + rB0) * K + cB0 * 8;
    const u16* gb1 = Bt + (size_t)(n0 + rB1) * K + cB1 * 8;
    const int loA = wave * 512, loB0 = wave * 1024, loB1 = wave * 1024 + 512;

    gl_lds16(ga, As + loA);
    gl_lds16(gb0, Bs + loB0);
    gl_lds16(gb1, Bs + loB1);

    f32x4 acc[2][4];
    #pragma unroll
    for (int i = 0; i < 2; ++i)
        #pragma unroll
        for (int j = 0; j < 4; ++j) acc[i][j] = (f32x4){0.f, 0.f, 0.f, 0.f};

    int ib = 0;
    for (int k0 = 0; k0 < K; k0 += 32, ib ^= 1) {
        __syncthreads();
        if (k0 + 32 < K) {
            gl_lds16(ga + k0 + 32,  As + (ib ^ 1) * 2048 + loA);
            gl_lds16(gb0 + k0 + 32, Bs + (ib ^ 1) * 4096 + loB0);
            gl_lds16(gb1 + k0 + 32, Bs + (ib ^ 1) * 4096 + loB1);
        }
        const u16* Ac = As + ib * 2048;
        const u16* Bc = Bs + ib * 4096;
        bf16x8 af[2], bfr[4];
        #pragma unroll
        for (int mt = 0; mt < 2; ++mt) {
            const int r = wm + mt * 16 + l16;
            af[mt] = *(const bf16x8*)&Ac[(r * 4 + ((qq + (r >> 1)) & 3)) * 8];
        }
        #pragma unroll
        for (int nt = 0; nt < 4; ++nt) {
            const int r = wn + nt * 16 + l16;
            bfr[nt] = *(const bf16x8*)&Bc[(r * 4 + ((qq + (r >> 1)) & 3)) * 8];
        }
        #pragma unroll
        for (int mt = 0; mt < 2; ++mt)
            #pragma unroll
            for (int nt = 0; nt < 4; ++nt)
                acc[mt][nt] = __builtin_amdgcn_mfma_f32_16x16x32_bf16(
                    af[mt], bfr[nt], acc[mt][nt], 0, 0, 0);
    }
    #pragma unroll
    for (int mt = 0; mt < 2; ++mt)
        #pragma unroll
        for (int r = 0; r < 4; ++r) {
            int grow = m0 + wm + mt * 16 + qq * 4 + r;
            #pragma unroll
            for (int nt = 0; nt < 4; ++nt)
                C[(size_t)grow * N + n0 + wn + nt * 16 + l16] = acc[mt][nt][r];
        }
}

// ---------------------------------------------------------------------------
// per-chunk local states via MFMA: St[d][e] = sum_j (v*lam^j)[d] (k*rk)[e]
// ---------------------------------------------------------------------------
__global__ __launch_bounds__(256) void state_local(
    const u16* __restrict__ kb, const u16* __restrict__ vb,
    const float* __restrict__ norms_k, const float* __restrict__ dlog,
    u16* __restrict__ statesb)
{
    __shared__ __align__(16) u16 vT[DD][SST];
    __shared__ __align__(16) u16 kT[DD][SST];
    const int c = blockIdx.x, bh = blockIdx.y;
    const int b = bh >> 2, h = bh & 3;
    const float lam = 1.f / (1.f + __expf(-dlog[h]));
    const float l2lam = log2f(lam);
    const int t = threadIdx.x;
    const int row0 = b * TT + c * QC;
    const size_t gbase = (size_t)row0 * CC + h * DD;

    {
        const int j2 = t & 31, d0 = (t >> 5) * 16;
        const int jj0 = 2 * j2, jj1 = jj0 + 1;
        const float w0 = exp2f((float)jj0 * l2lam);
        const float w1 = exp2f((float)jj1 * l2lam);
        const float rk0 = 1.f / fmaxf(sqrtf(norms_k[row0 + jj0]), EPS);
        const float rk1 = 1.f / fmaxf(sqrtf(norms_k[row0 + jj1]), EPS);
        u16 k0a[16], k1a[16], v0a[16], v1a[16];
        const u16* k0p = kb + gbase + (size_t)jj0 * CC + d0;
        const u16* k1p = kb + gbase + (size_t)jj1 * CC + d0;
        const u16* v0p = vb + gbase + (size_t)jj0 * CC + d0;
        const u16* v1p = vb + gbase + (size_t)jj1 * CC + d0;
        *(uint4*)&k0a[0] = *(const uint4*)k0p; *(uint4*)&k0a[8] = *(const uint4*)(k0p + 8);
        *(uint4*)&k1a[0] = *(const uint4*)k1p; *(uint4*)&k1a[8] = *(const uint4*)(k1p + 8);
        *(uint4*)&v0a[0] = *(const uint4*)v0p; *(uint4*)&v0a[8] = *(const uint4*)(v0p + 8);
        *(uint4*)&v1a[0] = *(const uint4*)v1p; *(uint4*)&v1a[8] = *(const uint4*)(v1p + 8);
        #pragma unroll
        for (int i = 0; i < 16; ++i) {
            unsigned int kw = (unsigned int)f2bu(bu2f(k0a[i]) * rk0)
                            | ((unsigned int)f2bu(bu2f(k1a[i]) * rk1) << 16);
            *(unsigned int*)&kT[d0 + i][jj0] = kw;
            unsigned int vw = (unsigned int)f2bu(bu2f(v0a[i]) * w0)
                            | ((unsigned int)f2bu(bu2f(v1a[i]) * w1) << 16);
            *(unsigned int*)&vT[d0 + i][jj0] = vw;
        }
    }
    __syncthreads();

    const int wave = t >> 6, lane = t & 63;
    const int quad = lane >> 4, l16 = lane & 15;
    f32x4 acc[2][8];
    #pragma unroll
    for (int i = 0; i < 2; ++i)
        #pragma unroll
        for (int j = 0; j < 8; ++j) acc[i][j] = (f32x4){0.f, 0.f, 0.f, 0.f};

    #pragma unroll
    for (int s = 0; s < 2; ++s) {
        bf16x8 af[2];
        #pragma unroll
        for (int mt = 0; mt < 2; ++mt)
            af[mt] = *(const bf16x8*)&vT[wave * 32 + mt * 16 + l16][s * 32 + quad * 8];
        #pragma unroll
        for (int nt = 0; nt < 8; ++nt) {
            bf16x8 bk = *(const bf16x8*)&kT[nt * 16 + l16][s * 32 + quad * 8];
            #pragma unroll
            for (int mt = 0; mt < 2; ++mt)
                acc[mt][nt] = __builtin_amdgcn_mfma_f32_16x16x32_bf16(
                    af[mt], bk, acc[mt][nt], 0, 0, 0);
        }
    }
    u16* so = statesb + ((size_t)(bh * NCH + c) << 14);
    #pragma unroll
    for (int mt = 0; mt < 2; ++mt)
        #pragma unroll
        for (int rr = 0; rr < 4; ++rr) {
            const int d = wave * 32 + mt * 16 + quad * 4 + rr;
            #pragma unroll
            for (int nt = 0; nt < 8; ++nt)
                so[(size_t)d * DD + nt * 16 + l16] = f2bu(acc[mt][nt][rr]);
        }
}

// ---------------------------------------------------------------------------
// suffix combine in place, software-pipelined (prefetch distance 1).
// ---------------------------------------------------------------------------
__global__ __launch_bounds__(256) void state_combine(
    const float* __restrict__ dlog, u16* __restrict__ statesb)
{
    const int bh = blockIdx.x >> 3, part = blockIdx.x & 7;
    const int h = bh & 3;
    const float lam = 1.f / (1.f + __expf(-dlog[h]));
    const float lamQ = exp2f((float)QC * log2f(lam));
    const int t = threadIdx.x;
    float run[8] = {};
    uint4* pbase = (uint4*)(statesb + ((size_t)(bh * NCH) << 14)) + part * 256 + t;
    uint4 cur = pbase[(size_t)(NCH - 1) * 2048];
    for (int c = NCH - 1; c >= 0; --c) {
        uint4 nxt = cur;
        if (c) nxt = pbase[(size_t)(c - 1) * 2048];
        u16* hb = (u16*)&cur;
        uint4 outw;
        u16* ho = (u16*)&outw;
        #pragma unroll
        for (int i = 0; i < 8; ++i) {
            float tmp = bu2f(hb[i]);
            ho[i] = f2bu(run[i]);
            run[i] = fmaf(lamQ, run[i], tmp);
        }
        pbase[(size_t)c * 2048] = outw;
        cur = nxt;
    }
}

// ---------------------------------------------------------------------------
// fused MFMA attention. Rotated-chunk LDS layout for q/k/St.
// ---------------------------------------------------------------------------
__global__ __launch_bounds__(256) void attention_fused(
    const u16* __restrict__ qb, const u16* __restrict__ kb,
    const u16* __restrict__ vb, const u16* __restrict__ statesb,
    const float* __restrict__ norms, const float* __restrict__ dlog,
    u16* __restrict__ retb)
{
    __shared__ __align__(16) u16 qks[2 * QC * DD];
    __shared__ __align__(16) u16 vsT[DD][SST];
    __shared__ __align__(16) u16 ss[QC][SST];
    __shared__ float rql[QC], rkl[QC];

    const int c = blockIdx.x, bh = blockIdx.y;
    const int b = bh >> 2, h = bh & 3;
    const float lam = 1.f / (1.f + __expf(-dlog[h]));
    const float l2lam = log2f(lam);
    const int t = threadIdx.x;
    const int row0 = b * TT + c * QC;
    const size_t base = (size_t)row0 * CC + h * DD;

    const int wave = t >> 6, lane = t & 63;
    const int quad = lane >> 4, l16 = lane & 15;
    const int r0 = wave * 16;

    {
        const int lrow = lane >> 4, cch = lane & 15;
        #pragma unroll
        for (int u = 0; u < 4; ++u) {
            const int R = wave * 16 + u * 4;
            const int gr = R + lrow;
            const int cq = (cch - gr) & 15;
            gl_lds16(qb + base + (size_t)gr * CC + cq * 8, &qks[R * DD]);
            gl_lds16(kb + base + (size_t)gr * CC + cq * 8, &qks[(QC + R) * DD]);
        }
    }
    if (t < QC)            rql[t]      = 1.f / fmaxf(sqrtf(norms[row0 + t]), EPS);
    else if (t < 2 * QC)   rkl[t - QC] = 1.f / fmaxf(sqrtf(norms[NROWS + row0 + t - QC]), EPS);
    {
        const int j2 = t & 31, d0 = (t >> 5) * 16;
        const u16* v0 = vb + base + (size_t)(2 * j2) * CC + d0;
        const u16* v1 = v0 + CC;
        uint4 a0 = *(const uint4*)v0;
        uint4 a1 = *(const uint4*)(v0 + 8);
        uint4 b0 = *(const uint4*)v1;
        uint4 b1 = *(const uint4*)(v1 + 8);
        const u16* ap0 = (const u16*)&a0; const u16* ap1 = (const u16*)&a1;
        const u16* bp0 = (const u16*)&b0; const u16* bp1 = (const u16*)&b1;
        #pragma unroll
        for (int i = 0; i < 8; ++i) {
            *(unsigned int*)&vsT[d0 + i][2 * j2] =
                (unsigned int)ap0[i] | ((unsigned int)bp0[i] << 16);
            *(unsigned int*)&vsT[d0 + 8 + i][2 * j2] =
                (unsigned int)ap1[i] | ((unsigned int)bp1[i] << 16);
        }
    }
    __syncthreads();

    bf16x8 aq[4];
    #pragma unroll
    for (int kq = 0; kq < 4; ++kq) {
        const int r = r0 + l16;
        aq[kq] = *(const bf16x8*)&qks[r * DD + ((kq * 4 + quad + r) & 15) * 8];
    }

    f32x4 accs[4];
    #pragma unroll
    for (int nt = 0; nt < 4; ++nt) accs[nt] = (f32x4){0.f, 0.f, 0.f, 0.f};
    #pragma unroll
    for (int nt = 0; nt < 4; ++nt)
        #pragma unroll
        for (int kq = 0; kq < 4; ++kq) {
            const int rk_ = nt * 16 + l16;
            bf16x8 bk = *(const bf16x8*)&qks[(QC + rk_) * DD + ((kq * 4 + quad + rk_) & 15) * 8];
            accs[nt] = __builtin_amdgcn_mfma_f32_16x16x32_bf16(aq[kq], bk, accs[nt], 0, 0, 0);
        }

    #pragma unroll
    for (int nt = 0; nt < 4; ++nt) {
        const int j = nt * 16 + l16;
        const float rkj = rkl[j];
        #pragma unroll
        for (int rr = 0; rr < 4; ++rr) {
            const int i = r0 + quad * 4 + rr;
            const int di = j - i;
            float p = (di > 0) ? accs[nt][rr] * exp2f((float)(di - 1) * l2lam) * rkj : 0.f;
            ss[i][j] = f2bu(p);
        }
    }
    __syncthreads();

    const u16* sb = statesb + ((size_t)(bh * NCH + c) << 14);
    {
        const int drow = lane >> 4, cch = lane & 15;
        #pragma unroll
        for (int u = 0; u < 8; ++u) {
            const int D = wave * 32 + u * 4;
            const int gd = D + drow;
            const int cq = (cch - gd) & 15;
            gl_lds16(sb + (size_t)gd * DD + cq * 8, &qks[D * DD]);
        }
    }
    bf16x8 ap[2];
    #pragma unroll
    for (int kj = 0; kj < 2; ++kj)
        ap[kj] = *(const bf16x8*)&ss[r0 + l16][kj * 32 + quad * 8];
    f32x4 accd[8];
    #pragma unroll
    for (int nt = 0; nt < 8; ++nt) accd[nt] = (f32x4){0.f, 0.f, 0.f, 0.f};
    #pragma unroll
    for (int nt = 0; nt < 8; ++nt)
        #pragma unroll
        for (int kj = 0; kj < 2; ++kj) {
            bf16x8 bv = *(const bf16x8*)&vsT[nt * 16 + l16][kj * 32 + quad * 8];
            accd[nt] = __builtin_amdgcn_mfma_f32_16x16x32_bf16(ap[kj], bv, accd[nt], 0, 0, 0);
        }
    __syncthreads();

    f32x4 accc[8];
    #pragma unroll
    for (int nt = 0; nt < 8; ++nt) accc[nt] = (f32x4){0.f, 0.f, 0.f, 0.f};
    #pragma unroll
    for (int nt = 0; nt < 8; ++nt)
        #pragma unroll
        for (int kq = 0; kq < 4; ++kq) {
            const int d = nt * 16 + l16;
            bf16x8 bs_ = *(const bf16x8*)&qks[d * DD + ((kq * 4 + quad + d) & 15) * 8];
            accc[nt] = __builtin_amdgcn_mfma_f32_16x16x32_bf16(aq[kq], bs_, accc[nt], 0, 0, 0);
        }

    u16* rb = retb + (size_t)row0 * CC + h * DD;
    #pragma unroll
    for (int rr = 0; rr < 4; ++rr) {
        const int ii = r0 + quad * 4 + rr;
        const float wrow = exp2f((float)(QC - 1 - ii) * l2lam);
        const float rq = rql[ii];
        #pragma unroll
        for (int nt = 0; nt < 8; ++nt) {
            float val = (accd[nt][rr] + wrow * accc[nt][rr]) * rq;
            rb[(size_t)ii * CC + nt * 16 + l16] = f2bu(val);
        }
    }
}

// ---------------------------------------------------------------------------
extern "C" void kernel_launch(void* const* d_in, const int* in_sizes, int n_in,
                              void* d_out, int out_size, void* d_ws, size_t ws_size,
                              hipStream_t stream) {
    const float* x         = (const float*)d_in[0];
    const float* basis     = (const float*)d_in[1];
    const float* qw        = (const float*)d_in[2];
    const float* kw        = (const float*)d_in[3];
    const float* v_coeffs  = (const float*)d_in[4];
    const float* o_coeffs  = (const float*)d_in[5];
    const float* dlog      = (const float*)d_in[6];
    const float* out_scale = (const float*)d_in[7];
    float* out             = (float*)d_out;

    u16* p = (u16*)d_ws;
    u16* qb      = p;                                   // 8192*512 bf16
    u16* kb      = qb + (size_t)NROWS * CC;
    u16* vb      = kb + (size_t)NROWS * CC;
    u16* statesb = vb + (size_t)NROWS * CC;             // 16*32*16384 bf16
    u16* xb      = statesb + (size_t)BB * HH * NCH * DD * DD;
    u16* retb    = xb;                                  // alias: xb dead after projections
    u16* wcat    = xb + (size_t)NROWS * CC;             // 3 x 512x512 bf16
    u16* o_ws    = wcat + 3 * (size_t)VV * CC;
    float* norms = (float*)(o_ws + (size_t)VV * CC);    // 2 x 8192 fp32 (q, k)
    u16* bab     = (u16*)(norms + 2 * NROWS);           // 512*128 bf16
    u16* vcb     = bab + (size_t)VV * NB2;
    u16* ocb     = vcb + (size_t)VV * NB2;

    // 1. casts / transposes / norm-zero in one launch
    prep_all<<<PREP_CVT + PREP_TR + 3 * PREP_CB + PREP_Z, 256, 0, stream>>>(
        x, qw, kw, basis, v_coeffs, o_coeffs, out_scale,
        xb, wcat, wcat + (size_t)VV * CC, bab, vcb, ocb, norms);
    // 2. weight GEMMs via MFMA (v_wT -> wcat sec 2, o_ws)
    gemm_w<<<dim3(8, 4), 256, 0, stream>>>(bab, vcb, ocb,
                                           wcat + 2 * (size_t)VV * CC, o_ws);
    // 3. fused q/k/v projection (A-tile shared across sections)
    gemm_qkv_fused<<<dim3(4, NROWS / 128), 256, 0, stream>>>(xb, wcat, qb, kb, vb,
                                                             norms);
    // 4. chunked linear attention (all-MFMA; norms applied downstream)
    state_local  <<<dim3(NCH, BB * HH), 256, 0, stream>>>(kb, vb, norms + NROWS,
                                                          dlog, statesb);
    state_combine<<<BB * HH * 8, 256, 0, stream>>>(dlog, statesb);
    attention_fused<<<dim3(NCH, BB * HH), 256, 0, stream>>>(qb, kb, vb, statesb,
                                                            norms, dlog, retb);
    // 5. output projection (o_ws includes out_scale), fp32 out
    gemm_out64<<<dim3(VV / 128, NROWS / 64), 256, 0, stream>>>(retb, o_ws, out);
}